// Round 1
// baseline (3395.439 us; speedup 1.0000x reference)
//
#include <hip/hip_runtime.h>
#include <hip/hip_bf16.h>

#define EPS 1e-5f

// ---------------------------------------------------------------- utilities
__device__ __forceinline__ unsigned int fkey(float f) {
    unsigned int b = __float_as_uint(f);
    return (b & 0x80000000u) ? ~b : (b | 0x80000000u);
}
__device__ __forceinline__ float funkey(unsigned int k) {
    unsigned int b = (k & 0x80000000u) ? (k & 0x7fffffffu) : ~k;
    return __uint_as_float(b);
}

// ------------------------------------------------------------ transpose W: Wt[c][o] = W[o][c]
__global__ void transpose_w_kernel(const float* __restrict__ W, int CO, int CIN,
                                   float* __restrict__ Wt) {
    int id = blockIdx.x * 256 + threadIdx.x;
    if (id >= CO * CIN) return;
    int o = id % CO, c = id / CO;
    Wt[id] = W[o * CIN + c];
}

// ------------------------------------------------------------ transpose feat: xT[b][c][m]
__global__ void transpose_feat_kernel(const float* __restrict__ feat, int fstride, int C,
                                      float* __restrict__ xT) {
    const int N = 2048;
    int id = blockIdx.x * 256 + threadIdx.x;
    if (id >= 8 * C * N) return;
    int m = id & 2047;
    int bc = id >> 11;
    int c = bc % C, b = bc / C;
    xT[id] = feat[((size_t)b * N + m) * fstride + c];
}

// ------------------------------------------------------------ xx[b][n] = sum_c x^2
__global__ void sumsq_kernel(const float* __restrict__ xT, int C, float* __restrict__ xx) {
    const int N = 2048;
    int id = blockIdx.x * 256 + threadIdx.x;
    if (id >= 8 * N) return;
    int b = id >> 11, n = id & 2047;
    const float* p = xT + (size_t)b * C * N + n;
    float s = 0.f;
    for (int c = 0; c < C; ++c) { float v = p[(size_t)c * N]; s = fmaf(v, v, s); }
    xx[id] = s;
}

// ------------------------------------------------------------ distance row + top-20
// one block per (b,n); 256 threads
__global__ void dist_topk_kernel(const float* __restrict__ xT, const float* __restrict__ xx,
                                 int C, int* __restrict__ idxOut) {
    const int N = 2048, K = 20;
    int b = blockIdx.x >> 11;
    int n = blockIdx.x & 2047;
    int tid = threadIdx.x;
    __shared__ float xr[128];
    __shared__ float dist[2048];
    __shared__ float rv[4];
    __shared__ int   ri[4];
    const float* xTb = xT + (size_t)b * C * N;
    if (tid < C) xr[tid] = xTb[(size_t)tid * N + n];
    __syncthreads();
    float xxn = xx[b * N + n];
    float acc[8];
#pragma unroll
    for (int j = 0; j < 8; ++j) acc[j] = 0.f;
    for (int c = 0; c < C; ++c) {
        float xc = xr[c];
        const float* row = xTb + (size_t)c * N;
#pragma unroll
        for (int j = 0; j < 8; ++j) acc[j] = fmaf(xc, row[tid + j * 256], acc[j]);
    }
#pragma unroll
    for (int j = 0; j < 8; ++j) {
        int m = tid + j * 256;
        dist[m] = 2.f * acc[j] - xxn - xx[b * N + m];
    }
    __syncthreads();

    int lane = tid & 63, wave = tid >> 6;
    for (int k = 0; k < K; ++k) {
        float bv = -INFINITY; int bi = 0x7fffffff;
#pragma unroll
        for (int j = 0; j < 8; ++j) {
            int m = tid + j * 256;
            float v = dist[m];
            if (v > bv || (v == bv && m < bi)) { bv = v; bi = m; }
        }
#pragma unroll
        for (int s = 32; s > 0; s >>= 1) {
            float ov = __shfl_xor(bv, s);
            int   oi = __shfl_xor(bi, s);
            if (ov > bv || (ov == bv && oi < bi)) { bv = ov; bi = oi; }
        }
        if (lane == 0) { rv[wave] = bv; ri[wave] = bi; }
        __syncthreads();
        if (tid == 0) {
            float fv = rv[0]; int fi = ri[0];
            for (int w = 1; w < 4; ++w)
                if (rv[w] > fv || (rv[w] == fv && ri[w] < fi)) { fv = rv[w]; fi = ri[w]; }
            idxOut[((size_t)b * N + n) * K + k] = fi;
            dist[fi] = -INFINITY;
        }
        __syncthreads();
    }
}

// ------------------------------------------------------------ edgeconv (fused matmul+BN+LReLU+maxK)
// one block per (b,n); 256 threads; writes into xcat slice (row stride 512)
template <int CI, int CO>
__global__ void edgeconv_kernel(const float* __restrict__ feat, int fstride,
                                const int* __restrict__ idx,
                                const float* __restrict__ Wt,
                                const float* __restrict__ gp, const float* __restrict__ bp,
                                const float* __restrict__ mp, const float* __restrict__ vp,
                                float* __restrict__ outBase) {
    const int N = 2048, K = 20;
    constexpr int C2 = 2 * CI;
    constexpr int NG = 256 / CO;   // k-groups
    constexpr int KG = K / NG;     // k's per group
    int b = blockIdx.x >> 11, n = blockIdx.x & 2047;
    int tid = threadIdx.x;
    __shared__ float xn[CI];
    __shared__ int   nb[K];
    __shared__ float edge[K * C2];
    __shared__ float red[256];
    size_t rowN = ((size_t)b * N + n) * fstride;
    if (tid < CI) xn[tid] = feat[rowN + tid];
    if (tid >= 64 && tid < 64 + K) nb[tid - 64] = idx[((size_t)b * N + n) * K + (tid - 64)];
    __syncthreads();
    for (int e = tid; e < K * C2; e += 256) {
        int k = e / C2, c = e - k * C2;
        float v;
        if (c < CI) v = xn[c];
        else {
            int c2 = c - CI;
            v = feat[((size_t)b * N + nb[k]) * fstride + c2] - xn[c2];
        }
        edge[e] = v;
    }
    __syncthreads();
    int o = tid % CO, kg = tid / CO;
    float acc[KG];
#pragma unroll
    for (int kk = 0; kk < KG; ++kk) acc[kk] = 0.f;
    const float* ep = edge + kg * KG * C2;
    for (int c = 0; c < C2; ++c) {
        float w = Wt[c * CO + o];
#pragma unroll
        for (int kk = 0; kk < KG; ++kk) acc[kk] = fmaf(w, ep[kk * C2 + c], acc[kk]);
    }
    float s  = gp[o] * rsqrtf(vp[o] + EPS);
    float sh = bp[o] - mp[o] * s;
    float hmax = -INFINITY;
#pragma unroll
    for (int kk = 0; kk < KG; ++kk) {
        float h = fmaf(acc[kk], s, sh);
        h = h > 0.f ? h : 0.2f * h;
        hmax = fmaxf(hmax, h);
    }
    if (NG > 1) {
        red[tid] = hmax;
        __syncthreads();
        if (kg == 0)
            for (int g2 = 1; g2 < NG; ++g2) hmax = fmaxf(hmax, red[g2 * CO + o]);
    }
    if (kg == 0) outBase[((size_t)b * N + n) * 512 + o] = hmax;
}

// ------------------------------------------------------------ global 512x512 matmul + BN+LReLU + max over N
// one block per (b, 8-row chunk); 256 threads, each owns o and o+256
__global__ void global_kernel(const float* __restrict__ xcat, const float* __restrict__ wgt,
                              const float* __restrict__ gg, const float* __restrict__ bg,
                              const float* __restrict__ mg, const float* __restrict__ vg,
                              unsigned int* __restrict__ keys) {
    const int N = 2048, CV = 512, TN = 8;
    int b   = blockIdx.x >> 8;
    int nb0 = (blockIdx.x & 255) * TN;
    int tid = threadIdx.x;
    __shared__ float xr[TN][CV];
    for (int e = tid; e < TN * CV; e += 256) {
        int t = e >> 9, c = e & 511;
        xr[t][c] = xcat[((size_t)b * N + nb0 + t) * CV + c];
    }
    __syncthreads();
    int o0 = tid, o1 = tid + 256;
    float acc0[TN], acc1[TN];
#pragma unroll
    for (int t = 0; t < TN; ++t) { acc0[t] = 0.f; acc1[t] = 0.f; }
    for (int c = 0; c < CV; ++c) {
        float w0 = wgt[c * CV + o0];
        float w1 = wgt[c * CV + o1];
#pragma unroll
        for (int t = 0; t < TN; ++t) {
            acc0[t] = fmaf(w0, xr[t][c], acc0[t]);
            acc1[t] = fmaf(w1, xr[t][c], acc1[t]);
        }
    }
    float s0 = gg[o0] * rsqrtf(vg[o0] + EPS), sh0 = bg[o0] - mg[o0] * s0;
    float s1 = gg[o1] * rsqrtf(vg[o1] + EPS), sh1 = bg[o1] - mg[o1] * s1;
    float m0 = -INFINITY, m1 = -INFINITY;
#pragma unroll
    for (int t = 0; t < TN; ++t) {
        float h0 = fmaf(acc0[t], s0, sh0); h0 = h0 > 0.f ? h0 : 0.2f * h0;
        float h1 = fmaf(acc1[t], s1, sh1); h1 = h1 > 0.f ? h1 : 0.2f * h1;
        m0 = fmaxf(m0, h0); m1 = fmaxf(m1, h1);
    }
    atomicMax(&keys[b * 512 + o0], fkey(m0));
    atomicMax(&keys[b * 512 + o1], fkey(m1));
}

__global__ void decode_kernel(const unsigned int* __restrict__ keys, float* __restrict__ out) {
    int id = blockIdx.x * 256 + threadIdx.x;
    if (id < 8 * 512) out[id] = funkey(keys[id]);
}

// ---------------------------------------------------------------- launcher
extern "C" void kernel_launch(void* const* d_in, const int* in_sizes, int n_in,
                              void* d_out, int out_size, void* d_ws, size_t ws_size,
                              hipStream_t stream) {
    const int B = 8, N = 2048, K = 20;
    const float* pts = (const float*)d_in[0];
    const float* w1 = (const float*)d_in[1];
    const float *g1 = (const float*)d_in[2], *b1 = (const float*)d_in[3],
                *m1 = (const float*)d_in[4], *v1 = (const float*)d_in[5];
    const float* w2 = (const float*)d_in[6];
    const float *g2 = (const float*)d_in[7], *b2 = (const float*)d_in[8],
                *m2 = (const float*)d_in[9], *v2 = (const float*)d_in[10];
    const float* w3 = (const float*)d_in[11];
    const float *g3 = (const float*)d_in[12], *b3 = (const float*)d_in[13],
                *m3 = (const float*)d_in[14], *v3 = (const float*)d_in[15];
    const float* w4 = (const float*)d_in[16];
    const float *g4 = (const float*)d_in[17], *b4 = (const float*)d_in[18],
                *m4 = (const float*)d_in[19], *v4 = (const float*)d_in[20];
    const float* wg = (const float*)d_in[21];
    const float *gg = (const float*)d_in[22], *bg = (const float*)d_in[23],
                *mg = (const float*)d_in[24], *vg = (const float*)d_in[25];

    // workspace layout (floats)
    float* ws   = (float*)d_ws;
    float* xcat = ws;                                    // 8*2048*512
    float* xT   = xcat + (size_t)B * N * 512;            // up to 8*128*2048
    float* xx   = xT + (size_t)B * 128 * N;              // 8*2048
    int*   idx  = (int*)(xx + B * N);                    // 8*2048*20
    float* wt1  = (float*)(idx + (size_t)B * N * K);     // 6*64
    float* wt2  = wt1 + 6 * 64;                          // 128*64
    float* wt3  = wt2 + 128 * 64;                        // 128*128
    float* wt4  = wt3 + 128 * 128;                       // 256*256
    float* wgt  = wt4 + 256 * 256;                       // 512*512
    unsigned int* keys = (unsigned int*)(wgt + 512 * 512); // 8*512

    // transpose weights
    transpose_w_kernel<<<(64 * 6 + 255) / 256, 256, 0, stream>>>(w1, 64, 6, wt1);
    transpose_w_kernel<<<(64 * 128 + 255) / 256, 256, 0, stream>>>(w2, 64, 128, wt2);
    transpose_w_kernel<<<(128 * 128 + 255) / 256, 256, 0, stream>>>(w3, 128, 128, wt3);
    transpose_w_kernel<<<(256 * 256 + 255) / 256, 256, 0, stream>>>(w4, 256, 256, wt4);
    transpose_w_kernel<<<(512 * 512 + 255) / 256, 256, 0, stream>>>(wg, 512, 512, wgt);

    // ---- layer 1: C=3 -> 64, out offset 0
    transpose_feat_kernel<<<(B * 3 * N + 255) / 256, 256, 0, stream>>>(pts, 3, 3, xT);
    sumsq_kernel<<<(B * N + 255) / 256, 256, 0, stream>>>(xT, 3, xx);
    dist_topk_kernel<<<B * N, 256, 0, stream>>>(xT, xx, 3, idx);
    edgeconv_kernel<3, 64><<<B * N, 256, 0, stream>>>(pts, 3, idx, wt1, g1, b1, m1, v1, xcat + 0);

    // ---- layer 2: C=64 -> 64, in = x1 (off 0), out offset 64
    transpose_feat_kernel<<<(B * 64 * N + 255) / 256, 256, 0, stream>>>(xcat + 0, 512, 64, xT);
    sumsq_kernel<<<(B * N + 255) / 256, 256, 0, stream>>>(xT, 64, xx);
    dist_topk_kernel<<<B * N, 256, 0, stream>>>(xT, xx, 64, idx);
    edgeconv_kernel<64, 64><<<B * N, 256, 0, stream>>>(xcat + 0, 512, idx, wt2, g2, b2, m2, v2, xcat + 64);

    // ---- layer 3: C=64 -> 128, in = x2 (off 64), out offset 128
    transpose_feat_kernel<<<(B * 64 * N + 255) / 256, 256, 0, stream>>>(xcat + 64, 512, 64, xT);
    sumsq_kernel<<<(B * N + 255) / 256, 256, 0, stream>>>(xT, 64, xx);
    dist_topk_kernel<<<B * N, 256, 0, stream>>>(xT, xx, 64, idx);
    edgeconv_kernel<64, 128><<<B * N, 256, 0, stream>>>(xcat + 64, 512, idx, wt3, g3, b3, m3, v3, xcat + 128);

    // ---- layer 4: C=128 -> 256, in = x3 (off 128), out offset 256
    transpose_feat_kernel<<<(B * 128 * N + 255) / 256, 256, 0, stream>>>(xcat + 128, 512, 128, xT);
    sumsq_kernel<<<(B * N + 255) / 256, 256, 0, stream>>>(xT, 128, xx);
    dist_topk_kernel<<<B * N, 256, 0, stream>>>(xT, xx, 128, idx);
    edgeconv_kernel<128, 256><<<B * N, 256, 0, stream>>>(xcat + 128, 512, idx, wt4, g4, b4, m4, v4, xcat + 256);

    // ---- global layer + max over N
    hipMemsetAsync(keys, 0, (size_t)B * 512 * sizeof(unsigned int), stream);
    global_kernel<<<B * 256, 256, 0, stream>>>(xcat, wgt, gg, bg, mg, vg, keys);
    decode_kernel<<<(B * 512 + 255) / 256, 256, 0, stream>>>(keys, (float*)d_out);
}

// Round 2
// 2129.768 us; speedup vs baseline: 1.5943x; 1.5943x over previous
//
#include <hip/hip_runtime.h>
#include <hip/hip_bf16.h>

#define EPS 1e-5f

// ---------------------------------------------------------------- utilities
__device__ __forceinline__ unsigned int fkey(float f) {
    unsigned int b = __float_as_uint(f);
    return (b & 0x80000000u) ? ~b : (b | 0x80000000u);
}
__device__ __forceinline__ float funkey(unsigned int k) {
    unsigned int b = (k & 0x80000000u) ? (k & 0x7fffffffu) : ~k;
    return __uint_as_float(b);
}

// ------------------------------------------------------------ transpose W: Wt[c][o] = W[o][c]
__global__ void transpose_w_kernel(const float* __restrict__ W, int CO, int CIN,
                                   float* __restrict__ Wt) {
    int id = blockIdx.x * 256 + threadIdx.x;
    if (id >= CO * CIN) return;
    int o = id % CO, c = id / CO;
    Wt[id] = W[o * CIN + c];
}

// ------------------------------------------------------------ transpose feat: xT[b][c][m]
__global__ void transpose_feat_kernel(const float* __restrict__ feat, int fstride, int C,
                                      float* __restrict__ xT) {
    const int N = 2048;
    int id = blockIdx.x * 256 + threadIdx.x;
    if (id >= 8 * C * N) return;
    int m = id & 2047;
    int bc = id >> 11;
    int c = bc % C, b = bc / C;
    xT[id] = feat[((size_t)b * N + m) * fstride + c];
}

// ------------------------------------------------------------ xx[b][n] = sum_c x^2
__global__ void sumsq_kernel(const float* __restrict__ xT, int C, float* __restrict__ xx) {
    const int N = 2048;
    int id = blockIdx.x * 256 + threadIdx.x;
    if (id >= 8 * N) return;
    int b = id >> 11, n = id & 2047;
    const float* p = xT + (size_t)b * C * N + n;
    float s = 0.f;
    for (int c = 0; c < C; ++c) { float v = p[(size_t)c * N]; s = fmaf(v, v, s); }
    xx[id] = s;
}

// ------------------------------------------------------------ distance tile + wave-local top-20
// block = 256 threads, handles TM=4 query rows; grid = B * (N/4)
__global__ void dist_topk_kernel(const float* __restrict__ xT, const float* __restrict__ xx,
                                 int C, int* __restrict__ idxOut) {
    const int N = 2048, K = 20, TM = 4;
    int b  = blockIdx.x >> 9;              // N/TM = 512 chunks
    int n0 = (blockIdx.x & 511) * TM;
    int tid = threadIdx.x;
    __shared__ float dist[TM][N];          // 32 KB

    const float* xTb = xT + (size_t)b * C * N;

    // ---------------- phase A: dot products, 4 rows x 8 cols per thread
    float acc[TM][8];
#pragma unroll
    for (int r = 0; r < TM; ++r)
#pragma unroll
        for (int i = 0; i < 8; ++i) acc[r][i] = 0.f;

#pragma unroll 2
    for (int c = 0; c < C; ++c) {
        const float* row = xTb + (size_t)c * N;
        float4 c0 = *(const float4*)(row + 4 * tid);          // cols 4*tid + i
        float4 c1 = *(const float4*)(row + 1024 + 4 * tid);   // cols 1024 + 4*tid + i
        float q[TM];
#pragma unroll
        for (int r = 0; r < TM; ++r) q[r] = row[n0 + r];      // wave-uniform
#pragma unroll
        for (int r = 0; r < TM; ++r) {
            acc[r][0] = fmaf(q[r], c0.x, acc[r][0]);
            acc[r][1] = fmaf(q[r], c0.y, acc[r][1]);
            acc[r][2] = fmaf(q[r], c0.z, acc[r][2]);
            acc[r][3] = fmaf(q[r], c0.w, acc[r][3]);
            acc[r][4] = fmaf(q[r], c1.x, acc[r][4]);
            acc[r][5] = fmaf(q[r], c1.y, acc[r][5]);
            acc[r][6] = fmaf(q[r], c1.z, acc[r][6]);
            acc[r][7] = fmaf(q[r], c1.w, acc[r][7]);
        }
    }
    {
        const float* xxb = xx + (size_t)b * N;
        float4 x0 = *(const float4*)(xxb + 4 * tid);
        float4 x1 = *(const float4*)(xxb + 1024 + 4 * tid);
        float xq[TM];
#pragma unroll
        for (int r = 0; r < TM; ++r) xq[r] = xxb[n0 + r];
#pragma unroll
        for (int r = 0; r < TM; ++r) {
            float4 d0, d1;
            d0.x = 2.f * acc[r][0] - xq[r] - x0.x;
            d0.y = 2.f * acc[r][1] - xq[r] - x0.y;
            d0.z = 2.f * acc[r][2] - xq[r] - x0.z;
            d0.w = 2.f * acc[r][3] - xq[r] - x0.w;
            d1.x = 2.f * acc[r][4] - xq[r] - x1.x;
            d1.y = 2.f * acc[r][5] - xq[r] - x1.y;
            d1.z = 2.f * acc[r][6] - xq[r] - x1.w * 0.f - x1.z;   // keep simple: fixed below
            d1.w = 2.f * acc[r][7] - xq[r] - x1.w;
            // (d1.z rewritten correctly)
            d1.z = 2.f * acc[r][6] - xq[r] - x1.z;
            *(float4*)&dist[r][4 * tid] = d0;
            *(float4*)&dist[r][1024 + 4 * tid] = d1;
        }
    }
    __syncthreads();

    // ---------------- phase B: wave-local top-20, one row per wave
    int lane = tid & 63;
    int r = tid >> 6;                       // wave id = row
    // lane's 32 elements: m = j*256 + 4*lane + i
    double key[8][4];
#pragma unroll
    for (int j = 0; j < 8; ++j) {
        float4 v = *(const float4*)&dist[r][j * 256 + 4 * lane];
        int m0 = j * 256 + 4 * lane;
        key[j][0] = (double)fkey(v.x) * 4096.0 + (double)(2047 - (m0 + 0));
        key[j][1] = (double)fkey(v.y) * 4096.0 + (double)(2047 - (m0 + 1));
        key[j][2] = (double)fkey(v.z) * 4096.0 + (double)(2047 - (m0 + 2));
        key[j][3] = (double)fkey(v.w) * 4096.0 + (double)(2047 - (m0 + 3));
    }
    double pkey = 1e300;
    int resm = 0;
    for (int k = 0; k < K; ++k) {
        double bk = -1.0;                   // all keys >= 0
#pragma unroll
        for (int j = 0; j < 8; ++j)
#pragma unroll
            for (int i = 0; i < 4; ++i) {
                double kk = key[j][i];
                bk = fmax(bk, kk < pkey ? kk : -1.0);
            }
#pragma unroll
        for (int s = 1; s < 64; s <<= 1)
            bk = fmax(bk, __shfl_xor(bk, s));
        pkey = bk;
        int m = 2047 - (int)(((long long)bk) & 4095);
        if (lane == k) resm = m;
    }
    if (lane < K) idxOut[((size_t)b * N + n0 + r) * K + lane] = resm;
}

// ------------------------------------------------------------ edgeconv (fused matmul+BN+LReLU+maxK)
// one block per (b,n); 256 threads; writes into xcat slice (row stride 512)
template <int CI, int CO>
__global__ void edgeconv_kernel(const float* __restrict__ feat, int fstride,
                                const int* __restrict__ idx,
                                const float* __restrict__ Wt,
                                const float* __restrict__ gp, const float* __restrict__ bp,
                                const float* __restrict__ mp, const float* __restrict__ vp,
                                float* __restrict__ outBase) {
    const int N = 2048, K = 20;
    constexpr int C2 = 2 * CI;
    constexpr int NG = 256 / CO;   // k-groups
    constexpr int KG = K / NG;     // k's per group
    int b = blockIdx.x >> 11, n = blockIdx.x & 2047;
    int tid = threadIdx.x;
    __shared__ float xn[CI];
    __shared__ int   nb[K];
    __shared__ float edge[K * C2];
    __shared__ float red[256];
    size_t rowN = ((size_t)b * N + n) * fstride;
    if (tid < CI) xn[tid] = feat[rowN + tid];
    if (tid >= 64 && tid < 64 + K) nb[tid - 64] = idx[((size_t)b * N + n) * K + (tid - 64)];
    __syncthreads();
    for (int e = tid; e < K * C2; e += 256) {
        int k = e / C2, c = e - k * C2;
        float v;
        if (c < CI) v = xn[c];
        else {
            int c2 = c - CI;
            v = feat[((size_t)b * N + nb[k]) * fstride + c2] - xn[c2];
        }
        edge[e] = v;
    }
    __syncthreads();
    int o = tid % CO, kg = tid / CO;
    float acc[KG];
#pragma unroll
    for (int kk = 0; kk < KG; ++kk) acc[kk] = 0.f;
    const float* ep = edge + kg * KG * C2;
    if constexpr (C2 % 4 == 0) {
        for (int c = 0; c < C2; c += 4) {
            float w0 = Wt[(c + 0) * CO + o];
            float w1 = Wt[(c + 1) * CO + o];
            float w2 = Wt[(c + 2) * CO + o];
            float w3 = Wt[(c + 3) * CO + o];
#pragma unroll
            for (int kk = 0; kk < KG; ++kk) {
                float4 ev = *(const float4*)&ep[kk * C2 + c];
                acc[kk] = fmaf(w0, ev.x, acc[kk]);
                acc[kk] = fmaf(w1, ev.y, acc[kk]);
                acc[kk] = fmaf(w2, ev.z, acc[kk]);
                acc[kk] = fmaf(w3, ev.w, acc[kk]);
            }
        }
    } else {
        for (int c = 0; c < C2; ++c) {
            float w = Wt[c * CO + o];
#pragma unroll
            for (int kk = 0; kk < KG; ++kk) acc[kk] = fmaf(w, ep[kk * C2 + c], acc[kk]);
        }
    }
    float s  = gp[o] * rsqrtf(vp[o] + EPS);
    float sh = bp[o] - mp[o] * s;
    float hmax = -INFINITY;
#pragma unroll
    for (int kk = 0; kk < KG; ++kk) {
        float h = fmaf(acc[kk], s, sh);
        h = h > 0.f ? h : 0.2f * h;
        hmax = fmaxf(hmax, h);
    }
    if (NG > 1) {
        red[tid] = hmax;
        __syncthreads();
        if (kg == 0)
            for (int g2 = 1; g2 < NG; ++g2) hmax = fmaxf(hmax, red[g2 * CO + o]);
    }
    if (kg == 0) outBase[((size_t)b * N + n) * 512 + o] = hmax;
}

// ------------------------------------------------------------ global 512x512 matmul + BN+LReLU + max over N
__global__ void global_kernel(const float* __restrict__ xcat, const float* __restrict__ wgt,
                              const float* __restrict__ gg, const float* __restrict__ bg,
                              const float* __restrict__ mg, const float* __restrict__ vg,
                              unsigned int* __restrict__ keys) {
    const int N = 2048, CV = 512, TN = 8;
    int b   = blockIdx.x >> 8;
    int nb0 = (blockIdx.x & 255) * TN;
    int tid = threadIdx.x;
    __shared__ float xr[TN][CV];
    for (int e = tid; e < TN * CV; e += 256) {
        int t = e >> 9, c = e & 511;
        xr[t][c] = xcat[((size_t)b * N + nb0 + t) * CV + c];
    }
    __syncthreads();
    int o0 = tid, o1 = tid + 256;
    float acc0[TN], acc1[TN];
#pragma unroll
    for (int t = 0; t < TN; ++t) { acc0[t] = 0.f; acc1[t] = 0.f; }
    for (int c = 0; c < CV; ++c) {
        float w0 = wgt[c * CV + o0];
        float w1 = wgt[c * CV + o1];
#pragma unroll
        for (int t = 0; t < TN; ++t) {
            acc0[t] = fmaf(w0, xr[t][c], acc0[t]);
            acc1[t] = fmaf(w1, xr[t][c], acc1[t]);
        }
    }
    float s0 = gg[o0] * rsqrtf(vg[o0] + EPS), sh0 = bg[o0] - mg[o0] * s0;
    float s1 = gg[o1] * rsqrtf(vg[o1] + EPS), sh1 = bg[o1] - mg[o1] * s1;
    float m0 = -INFINITY, m1 = -INFINITY;
#pragma unroll
    for (int t = 0; t < TN; ++t) {
        float h0 = fmaf(acc0[t], s0, sh0); h0 = h0 > 0.f ? h0 : 0.2f * h0;
        float h1 = fmaf(acc1[t], s1, sh1); h1 = h1 > 0.f ? h1 : 0.2f * h1;
        m0 = fmaxf(m0, h0); m1 = fmaxf(m1, h1);
    }
    atomicMax(&keys[b * 512 + o0], fkey(m0));
    atomicMax(&keys[b * 512 + o1], fkey(m1));
}

__global__ void decode_kernel(const unsigned int* __restrict__ keys, float* __restrict__ out) {
    int id = blockIdx.x * 256 + threadIdx.x;
    if (id < 8 * 512) out[id] = funkey(keys[id]);
}

// ---------------------------------------------------------------- launcher
extern "C" void kernel_launch(void* const* d_in, const int* in_sizes, int n_in,
                              void* d_out, int out_size, void* d_ws, size_t ws_size,
                              hipStream_t stream) {
    const int B = 8, N = 2048, K = 20;
    const float* pts = (const float*)d_in[0];
    const float* w1 = (const float*)d_in[1];
    const float *g1 = (const float*)d_in[2], *b1 = (const float*)d_in[3],
                *m1 = (const float*)d_in[4], *v1 = (const float*)d_in[5];
    const float* w2 = (const float*)d_in[6];
    const float *g2 = (const float*)d_in[7], *b2 = (const float*)d_in[8],
                *m2 = (const float*)d_in[9], *v2 = (const float*)d_in[10];
    const float* w3 = (const float*)d_in[11];
    const float *g3 = (const float*)d_in[12], *b3 = (const float*)d_in[13],
                *m3 = (const float*)d_in[14], *v3 = (const float*)d_in[15];
    const float* w4 = (const float*)d_in[16];
    const float *g4 = (const float*)d_in[17], *b4 = (const float*)d_in[18],
                *m4 = (const float*)d_in[19], *v4 = (const float*)d_in[20];
    const float* wg = (const float*)d_in[21];
    const float *gg = (const float*)d_in[22], *bg = (const float*)d_in[23],
                *mg = (const float*)d_in[24], *vg = (const float*)d_in[25];

    // workspace layout (floats)
    float* ws   = (float*)d_ws;
    float* xcat = ws;                                    // 8*2048*512
    float* xT   = xcat + (size_t)B * N * 512;            // up to 8*128*2048
    float* xx   = xT + (size_t)B * 128 * N;              // 8*2048
    int*   idx  = (int*)(xx + B * N);                    // 8*2048*20
    float* wt1  = (float*)(idx + (size_t)B * N * K);     // 6*64
    float* wt2  = wt1 + 6 * 64;                          // 128*64
    float* wt3  = wt2 + 128 * 64;                        // 128*128
    float* wt4  = wt3 + 128 * 128;                       // 256*256
    float* wgt  = wt4 + 256 * 256;                       // 512*512
    unsigned int* keys = (unsigned int*)(wgt + 512 * 512); // 8*512

    // transpose weights
    transpose_w_kernel<<<(64 * 6 + 255) / 256, 256, 0, stream>>>(w1, 64, 6, wt1);
    transpose_w_kernel<<<(64 * 128 + 255) / 256, 256, 0, stream>>>(w2, 64, 128, wt2);
    transpose_w_kernel<<<(128 * 128 + 255) / 256, 256, 0, stream>>>(w3, 128, 128, wt3);
    transpose_w_kernel<<<(256 * 256 + 255) / 256, 256, 0, stream>>>(w4, 256, 256, wt4);
    transpose_w_kernel<<<(512 * 512 + 255) / 256, 256, 0, stream>>>(wg, 512, 512, wgt);

    // ---- layer 1: C=3 -> 64, out offset 0
    transpose_feat_kernel<<<(B * 3 * N + 255) / 256, 256, 0, stream>>>(pts, 3, 3, xT);
    sumsq_kernel<<<(B * N + 255) / 256, 256, 0, stream>>>(xT, 3, xx);
    dist_topk_kernel<<<B * (N / 4), 256, 0, stream>>>(xT, xx, 3, idx);
    edgeconv_kernel<3, 64><<<B * N, 256, 0, stream>>>(pts, 3, idx, wt1, g1, b1, m1, v1, xcat + 0);

    // ---- layer 2: C=64 -> 64, in = x1 (off 0), out offset 64
    transpose_feat_kernel<<<(B * 64 * N + 255) / 256, 256, 0, stream>>>(xcat + 0, 512, 64, xT);
    sumsq_kernel<<<(B * N + 255) / 256, 256, 0, stream>>>(xT, 64, xx);
    dist_topk_kernel<<<B * (N / 4), 256, 0, stream>>>(xT, xx, 64, idx);
    edgeconv_kernel<64, 64><<<B * N, 256, 0, stream>>>(xcat + 0, 512, idx, wt2, g2, b2, m2, v2, xcat + 64);

    // ---- layer 3: C=64 -> 128, in = x2 (off 64), out offset 128
    transpose_feat_kernel<<<(B * 64 * N + 255) / 256, 256, 0, stream>>>(xcat + 64, 512, 64, xT);
    sumsq_kernel<<<(B * N + 255) / 256, 256, 0, stream>>>(xT, 64, xx);
    dist_topk_kernel<<<B * (N / 4), 256, 0, stream>>>(xT, xx, 64, idx);
    edgeconv_kernel<64, 128><<<B * N, 256, 0, stream>>>(xcat + 64, 512, idx, wt3, g3, b3, m3, v3, xcat + 128);

    // ---- layer 4: C=128 -> 256, in = x3 (off 128), out offset 256
    transpose_feat_kernel<<<(B * 128 * N + 255) / 256, 256, 0, stream>>>(xcat + 128, 512, 128, xT);
    sumsq_kernel<<<(B * N + 255) / 256, 256, 0, stream>>>(xT, 128, xx);
    dist_topk_kernel<<<B * (N / 4), 256, 0, stream>>>(xT, xx, 128, idx);
    edgeconv_kernel<128, 256><<<B * N, 256, 0, stream>>>(xcat + 128, 512, idx, wt4, g4, b4, m4, v4, xcat + 256);

    // ---- global layer + max over N
    hipMemsetAsync(keys, 0, (size_t)B * 512 * sizeof(unsigned int), stream);
    global_kernel<<<B * 256, 256, 0, stream>>>(xcat, wgt, gg, bg, mg, vg, keys);
    decode_kernel<<<(B * 512 + 255) / 256, 256, 0, stream>>>(keys, (float*)d_out);
}

// Round 4
// 1174.253 us; speedup vs baseline: 2.8916x; 1.8137x over previous
//
#include <hip/hip_runtime.h>
#include <hip/hip_bf16.h>

#define EPS 1e-5f

typedef __attribute__((ext_vector_type(8))) short bf16x8;
typedef __attribute__((ext_vector_type(4))) float f32x4;

// ---------------------------------------------------------------- utilities
__device__ __forceinline__ unsigned int fkey(float f) {
    unsigned int b = __float_as_uint(f);
    return (b & 0x80000000u) ? ~b : (b | 0x80000000u);
}
__device__ __forceinline__ float funkey(unsigned int k) {
    unsigned int b = (k & 0x80000000u) ? (k & 0x7fffffffu) : ~k;
    return __uint_as_float(b);
}
__device__ __forceinline__ unsigned short f2bu(float f) {
    union { __hip_bfloat16 h; unsigned short u; } cv;
    cv.h = __float2bfloat16(f);
    return cv.u;
}
__device__ __forceinline__ float bu2f(unsigned short u) {
    return __uint_as_float(((unsigned int)u) << 16);
}
__device__ __forceinline__ void hilo(float v, unsigned short& h, unsigned short& l) {
    h = f2bu(v);
    l = f2bu(v - bu2f(h));
}

// ------------------------------------------------------------ weight fragment packing (hi+lo planes)
// F[(((ot*KS + ks)*64 + lane)*8 + j)] = bf16(W[o][c]), o = ot*16+(lane&15), c = ks*32+(lane>>4)*8+j
__global__ void wfrag_kernel(const float* __restrict__ W, int CO, int C2, int C2P,
                             unsigned short* __restrict__ Fh, unsigned short* __restrict__ Fl) {
    int id = blockIdx.x * 256 + threadIdx.x;
    int total = CO * C2P;
    if (id >= total) return;
    int j = id & 7, lane = (id >> 3) & 63, t = id >> 9;
    int KS = C2P >> 5;
    int ks = t % KS, ot = t / KS;
    int o = ot * 16 + (lane & 15);
    int c = ks * 32 + ((lane >> 4) << 3) + j;
    float v = (c < C2) ? W[o * C2 + c] : 0.f;
    unsigned short h, l;
    hilo(v, h, l);
    Fh[id] = h;
    Fl[id] = l;
}

// ------------------------------------------------------------ transpose feat: xT[b][c][m]
__global__ void transpose_feat_kernel(const float* __restrict__ feat, int fstride, int C,
                                      float* __restrict__ xT) {
    const int N = 2048;
    int id = blockIdx.x * 256 + threadIdx.x;
    if (id >= 8 * C * N) return;
    int m = id & 2047;
    int bc = id >> 11;
    int c = bc % C, b = bc / C;
    xT[id] = feat[((size_t)b * N + m) * fstride + c];
}

// ------------------------------------------------------------ xx[b][n] = sum_c x^2
__global__ void sumsq_kernel(const float* __restrict__ xT, int C, float* __restrict__ xx) {
    const int N = 2048;
    int id = blockIdx.x * 256 + threadIdx.x;
    if (id >= 8 * N) return;
    int b = id >> 11, n = id & 2047;
    const float* p = xT + (size_t)b * C * N + n;
    float s = 0.f;
    for (int c = 0; c < C; ++c) { float v = p[(size_t)c * N]; s = fmaf(v, v, s); }
    xx[id] = s;
}

// ------------------------------------------------------------ distance tile + wave-local top-20
__global__ void dist_topk_kernel(const float* __restrict__ xT, const float* __restrict__ xx,
                                 int C, int* __restrict__ idxOut) {
    const int N = 2048, TM = 4;
    int b  = blockIdx.x >> 9;
    int n0 = (blockIdx.x & 511) * TM;
    int tid = threadIdx.x;
    __shared__ float dist[TM][N];

    const float* xTb = xT + (size_t)b * C * N;

    float acc[TM][8];
#pragma unroll
    for (int r = 0; r < TM; ++r)
#pragma unroll
        for (int i = 0; i < 8; ++i) acc[r][i] = 0.f;

#pragma unroll 2
    for (int c = 0; c < C; ++c) {
        const float* row = xTb + (size_t)c * N;
        float4 c0 = *(const float4*)(row + 4 * tid);
        float4 c1 = *(const float4*)(row + 1024 + 4 * tid);
        float q[TM];
#pragma unroll
        for (int r = 0; r < TM; ++r) q[r] = row[n0 + r];
#pragma unroll
        for (int r = 0; r < TM; ++r) {
            acc[r][0] = fmaf(q[r], c0.x, acc[r][0]);
            acc[r][1] = fmaf(q[r], c0.y, acc[r][1]);
            acc[r][2] = fmaf(q[r], c0.z, acc[r][2]);
            acc[r][3] = fmaf(q[r], c0.w, acc[r][3]);
            acc[r][4] = fmaf(q[r], c1.x, acc[r][4]);
            acc[r][5] = fmaf(q[r], c1.y, acc[r][5]);
            acc[r][6] = fmaf(q[r], c1.z, acc[r][6]);
            acc[r][7] = fmaf(q[r], c1.w, acc[r][7]);
        }
    }
    {
        const float* xxb = xx + (size_t)b * N;
        float4 x0 = *(const float4*)(xxb + 4 * tid);
        float4 x1 = *(const float4*)(xxb + 1024 + 4 * tid);
        float xq[TM];
#pragma unroll
        for (int r = 0; r < TM; ++r) xq[r] = xxb[n0 + r];
#pragma unroll
        for (int r = 0; r < TM; ++r) {
            float4 d0, d1;
            d0.x = 2.f * acc[r][0] - xq[r] - x0.x;
            d0.y = 2.f * acc[r][1] - xq[r] - x0.y;
            d0.z = 2.f * acc[r][2] - xq[r] - x0.z;
            d0.w = 2.f * acc[r][3] - xq[r] - x0.w;
            d1.x = 2.f * acc[r][4] - xq[r] - x1.x;
            d1.y = 2.f * acc[r][5] - xq[r] - x1.y;
            d1.z = 2.f * acc[r][6] - xq[r] - x1.z;
            d1.w = 2.f * acc[r][7] - xq[r] - x1.w;
            *(float4*)&dist[r][4 * tid] = d0;
            *(float4*)&dist[r][1024 + 4 * tid] = d1;
        }
    }
    __syncthreads();

    int lane = tid & 63;
    int r = tid >> 6;
    double key[8][4];
#pragma unroll
    for (int j = 0; j < 8; ++j) {
        float4 v = *(const float4*)&dist[r][j * 256 + 4 * lane];
        int m0 = j * 256 + 4 * lane;
        key[j][0] = (double)fkey(v.x) * 4096.0 + (double)(2047 - (m0 + 0));
        key[j][1] = (double)fkey(v.y) * 4096.0 + (double)(2047 - (m0 + 1));
        key[j][2] = (double)fkey(v.z) * 4096.0 + (double)(2047 - (m0 + 2));
        key[j][3] = (double)fkey(v.w) * 4096.0 + (double)(2047 - (m0 + 3));
    }
    double pkey = 1e300;
    int resm = 0;
    for (int k = 0; k < 20; ++k) {
        double bk = -1.0;
#pragma unroll
        for (int j = 0; j < 8; ++j)
#pragma unroll
            for (int i = 0; i < 4; ++i) {
                double kk = key[j][i];
                bk = fmax(bk, kk < pkey ? kk : -1.0);
            }
#pragma unroll
        for (int s = 1; s < 64; s <<= 1)
            bk = fmax(bk, __shfl_xor(bk, s));
        pkey = bk;
        int m = 2047 - (int)(((long long)bk) & 4095);
        if (lane == k) resm = m;
    }
    if (lane < 20) idxOut[((size_t)b * N + n0 + r) * 20 + lane] = resm;
}

// ------------------------------------------------------------ MFMA edgeconv, hi/lo split (3 MFMA per product)
// Row mapping m = k*TN + ln. K-chunked (NKC chunks) to bound LDS; acc persists across chunks.
template <int CI, int CO, int TN, int WAVES, int NKC>
__global__ __launch_bounds__(WAVES * 64) void
edgeconv_mfma(const float* __restrict__ feat, int fs, const int* __restrict__ idx,
              const unsigned short* __restrict__ Wh, const unsigned short* __restrict__ Wl,
              const float* __restrict__ gp, const float* __restrict__ bp,
              const float* __restrict__ mp, const float* __restrict__ vp,
              float* __restrict__ outBase) {
    constexpr int N = 2048, K = 20;
    constexpr int C2 = 2 * CI;
    constexpr int C2P = (C2 < 32) ? 32 : C2;
    constexpr int KS = C2P / 32;
    constexpr int KSC = KS / NKC;          // ksteps per chunk
    constexpr int CCOLS = KSC * 32;        // bf16 cols per chunk
    constexpr int CHB = CCOLS * 2;         // bytes per row per chunk
    constexpr int OT = CO / 16;
    constexpr int OTW = OT / WAVES;
    constexpr int M = TN * K;
    constexpr int MT = M / 16;
    constexpr int NB = N / TN;
    constexpr int CH = CCOLS / 8;          // uint4 groups per row
    constexpr int SWZ = (CHB >= 128) ? 7 : (CHB / 16 - 1);
    constexpr int THREADS = WAVES * 64;

    int b  = blockIdx.x / NB;
    int n0 = (blockIdx.x % NB) * TN;
    int tid = threadIdx.x;
    int lane = tid & 63, wv = tid >> 6;

    __shared__ float ctr[TN][CI];
    __shared__ int nb[M];
    __shared__ __align__(16) unsigned char Eh[M * CHB];
    __shared__ __align__(16) unsigned char El[M * CHB];

    for (int e = tid; e < TN * CI; e += THREADS) {
        int ln = e / CI, c = e % CI;
        ctr[ln][c] = feat[((size_t)b * N + n0 + ln) * fs + c];
    }
    for (int e = tid; e < M; e += THREADS) {
        int k = e / TN, ln = e % TN;
        nb[e] = idx[((size_t)b * N + n0 + ln) * K + k];
    }
    __syncthreads();

    f32x4 acc[MT][OTW];
#pragma unroll
    for (int mt = 0; mt < MT; ++mt)
#pragma unroll
        for (int ot = 0; ot < OTW; ++ot)
#pragma unroll
            for (int rr = 0; rr < 4; ++rr) acc[mt][ot][rr] = 0.f;

    for (int kc = 0; kc < NKC; ++kc) {
        if (kc) __syncthreads();
        // -------- build chunk (hi+lo planes, swizzled)
        for (int e = tid; e < M * CH; e += THREADS) {
            int mrow = e / CH, ch = e - mrow * CH;
            int c0 = kc * CCOLS + ch * 8;          // global bf16 col
            int ln = mrow % TN;
            float v[8];
            if constexpr (CI >= 8) {
                if (c0 < CI) {
#pragma unroll
                    for (int j = 0; j < 8; ++j) v[j] = ctr[ln][c0 + j];
                } else {
                    int c1 = c0 - CI;
                    const float* nrow = feat + ((size_t)b * N + nb[mrow]) * fs + c1;
                    float4 a  = *(const float4*)nrow;
                    float4 b4 = *(const float4*)(nrow + 4);
                    v[0] = a.x  - ctr[ln][c1 + 0];
                    v[1] = a.y  - ctr[ln][c1 + 1];
                    v[2] = a.z  - ctr[ln][c1 + 2];
                    v[3] = a.w  - ctr[ln][c1 + 3];
                    v[4] = b4.x - ctr[ln][c1 + 4];
                    v[5] = b4.y - ctr[ln][c1 + 5];
                    v[6] = b4.z - ctr[ln][c1 + 6];
                    v[7] = b4.w - ctr[ln][c1 + 7];
                }
            } else {  // CI == 3
                if (c0 == 0) {
                    const float* nrow = feat + ((size_t)b * N + nb[mrow]) * fs;
                    v[0] = ctr[ln][0]; v[1] = ctr[ln][1]; v[2] = ctr[ln][2];
                    v[3] = nrow[0] - ctr[ln][0];
                    v[4] = nrow[1] - ctr[ln][1];
                    v[5] = nrow[2] - ctr[ln][2];
                    v[6] = 0.f; v[7] = 0.f;
                } else {
#pragma unroll
                    for (int j = 0; j < 8; ++j) v[j] = 0.f;
                }
            }
            union { unsigned short u[8]; uint4 v4; } th, tl;
#pragma unroll
            for (int j = 0; j < 8; ++j) hilo(v[j], th.u[j], tl.u[j]);
            int off = mrow * CHB + ((ch * 16) ^ ((mrow & SWZ) << 4));
            *(uint4*)&Eh[off] = th.v4;
            *(uint4*)&El[off] = tl.v4;
        }
        __syncthreads();

        // -------- B fragments for this chunk (resident)
        bf16x8 Bh[OTW][KSC], Bl[OTW][KSC];
#pragma unroll
        for (int ot = 0; ot < OTW; ++ot)
#pragma unroll
            for (int ksc = 0; ksc < KSC; ++ksc) {
                size_t fi = (size_t)((((wv * OTW + ot) * KS + kc * KSC + ksc) * 64 + lane)) << 3;
                Bh[ot][ksc] = *(const bf16x8*)(Wh + fi);
                Bl[ot][ksc] = *(const bf16x8*)(Wl + fi);
            }

        // -------- MFMA over row tiles
#pragma unroll
        for (int mt = 0; mt < MT; ++mt) {
            int r0 = mt * 16 + (lane & 15);
            int cb = (lane >> 4) << 4;
            bf16x8 Ah[KSC], Al[KSC];
#pragma unroll
            for (int ksc = 0; ksc < KSC; ++ksc) {
                int off = r0 * CHB + (((ksc << 6) + cb) ^ ((r0 & SWZ) << 4));
                Ah[ksc] = *(const bf16x8*)&Eh[off];
                Al[ksc] = *(const bf16x8*)&El[off];
            }
#pragma unroll
            for (int ksc = 0; ksc < KSC; ++ksc)
#pragma unroll
                for (int ot = 0; ot < OTW; ++ot) {
                    acc[mt][ot] = __builtin_amdgcn_mfma_f32_16x16x32_bf16(Al[ksc], Bh[ot][ksc], acc[mt][ot], 0, 0, 0);
                    acc[mt][ot] = __builtin_amdgcn_mfma_f32_16x16x32_bf16(Ah[ksc], Bl[ot][ksc], acc[mt][ot], 0, 0, 0);
                    acc[mt][ot] = __builtin_amdgcn_mfma_f32_16x16x32_bf16(Ah[ksc], Bh[ot][ksc], acc[mt][ot], 0, 0, 0);
                }
        }
    }

    // -------- epilogue: max over k (mt + lane groups), BN+LReLU (monotone), store
#pragma unroll
    for (int ot = 0; ot < OTW; ++ot) {
        f32x4 v;
#pragma unroll
        for (int rr = 0; rr < 4; ++rr) {
            float m = acc[0][ot][rr];
#pragma unroll
            for (int mt = 1; mt < MT; ++mt) m = fmaxf(m, acc[mt][ot][rr]);
            if constexpr (TN == 4) m = fmaxf(m, __shfl_xor(m, 16));
            m = fmaxf(m, __shfl_xor(m, 32));
            v[rr] = m;
        }
        int o = (wv * OTW + ot) * 16 + (lane & 15);
        float s  = gp[o] * rsqrtf(vp[o] + EPS);
        float sh = bp[o] - mp[o] * s;
        bool valid = (TN == 8) ? (lane < 32) : (lane < 16);
        if (valid) {
            int lnb = (TN == 8) ? ((lane >> 4) << 2) : 0;
#pragma unroll
            for (int rr = 0; rr < 4; ++rr) {
                float h = fmaf(v[rr], s, sh);
                h = h > 0.f ? h : 0.2f * h;
                outBase[((size_t)b * N + n0 + lnb + rr) * 512 + o] = h;
            }
        }
    }
}

// ------------------------------------------------------------ global 512x512 MFMA (hi/lo) + BN+LReLU + max over N
__global__ __launch_bounds__(256) void
global_mfma(const float* __restrict__ xcat,
            const unsigned short* __restrict__ Wh, const unsigned short* __restrict__ Wl,
            const float* __restrict__ gg, const float* __restrict__ bg,
            const float* __restrict__ mg, const float* __restrict__ vg,
            unsigned int* __restrict__ keys) {
    const int N = 2048, CV = 512;
    int b  = blockIdx.x >> 5;
    int n0 = (blockIdx.x & 31) * 64;
    int tid = threadIdx.x, lane = tid & 63, wv = tid >> 6;

    f32x4 runmax[8];
#pragma unroll
    for (int ot = 0; ot < 8; ++ot)
#pragma unroll
        for (int rr = 0; rr < 4; ++rr) runmax[ot][rr] = -INFINITY;

    for (int mt = 0; mt < 4; ++mt) {
        int rown = n0 + mt * 16 + (lane & 15);
        const float* arow = xcat + ((size_t)b * N + rown) * CV + ((lane >> 4) << 3);
        bf16x8 Ah[16], Al[16];
#pragma unroll
        for (int ks = 0; ks < 16; ++ks) {
            float4 a  = *(const float4*)(arow + ks * 32);
            float4 b4 = *(const float4*)(arow + ks * 32 + 4);
            union { unsigned short u[8]; bf16x8 v; } ch, cl;
            hilo(a.x,  ch.u[0], cl.u[0]);
            hilo(a.y,  ch.u[1], cl.u[1]);
            hilo(a.z,  ch.u[2], cl.u[2]);
            hilo(a.w,  ch.u[3], cl.u[3]);
            hilo(b4.x, ch.u[4], cl.u[4]);
            hilo(b4.y, ch.u[5], cl.u[5]);
            hilo(b4.z, ch.u[6], cl.u[6]);
            hilo(b4.w, ch.u[7], cl.u[7]);
            Ah[ks] = ch.v; Al[ks] = cl.v;
        }
#pragma unroll
        for (int ot = 0; ot < 8; ++ot) {
            f32x4 acc;
#pragma unroll
            for (int rr = 0; rr < 4; ++rr) acc[rr] = 0.f;
#pragma unroll
            for (int ks = 0; ks < 16; ++ks) {
                size_t fi = (size_t)((((wv * 8 + ot) * 16 + ks) * 64 + lane)) << 3;
                bf16x8 Bh = *(const bf16x8*)(Wh + fi);
                bf16x8 Bl = *(const bf16x8*)(Wl + fi);
                acc = __builtin_amdgcn_mfma_f32_16x16x32_bf16(Al[ks], Bh, acc, 0, 0, 0);
                acc = __builtin_amdgcn_mfma_f32_16x16x32_bf16(Ah[ks], Bl, acc, 0, 0, 0);
                acc = __builtin_amdgcn_mfma_f32_16x16x32_bf16(Ah[ks], Bh, acc, 0, 0, 0);
            }
#pragma unroll
            for (int rr = 0; rr < 4; ++rr) runmax[ot][rr] = fmaxf(runmax[ot][rr], acc[rr]);
        }
    }
#pragma unroll
    for (int ot = 0; ot < 8; ++ot) {
        f32x4 v = runmax[ot];
#pragma unroll
        for (int rr = 0; rr < 4; ++rr) {
            v[rr] = fmaxf(v[rr], __shfl_xor(v[rr], 16));
            v[rr] = fmaxf(v[rr], __shfl_xor(v[rr], 32));
        }
        int o = wv * 128 + ot * 16 + (lane & 15);
        float s  = gg[o] * rsqrtf(vg[o] + EPS);
        float sh = bg[o] - mg[o] * s;
        if (lane < 16) {
            float hm = -INFINITY;
#pragma unroll
            for (int rr = 0; rr < 4; ++rr) {
                float h = fmaf(v[rr], s, sh);
                h = h > 0.f ? h : 0.2f * h;
                hm = fmaxf(hm, h);
            }
            atomicMax(&keys[b * 512 + o], fkey(hm));
        }
    }
}

__global__ void decode_kernel(const unsigned int* __restrict__ keys, float* __restrict__ out) {
    int id = blockIdx.x * 256 + threadIdx.x;
    if (id < 8 * 512) out[id] = funkey(keys[id]);
}

// ---------------------------------------------------------------- launcher
extern "C" void kernel_launch(void* const* d_in, const int* in_sizes, int n_in,
                              void* d_out, int out_size, void* d_ws, size_t ws_size,
                              hipStream_t stream) {
    const int B = 8, N = 2048, K = 20;
    const float* pts = (const float*)d_in[0];
    const float* w1 = (const float*)d_in[1];
    const float *g1 = (const float*)d_in[2], *b1 = (const float*)d_in[3],
                *m1 = (const float*)d_in[4], *v1 = (const float*)d_in[5];
    const float* w2 = (const float*)d_in[6];
    const float *g2 = (const float*)d_in[7], *b2 = (const float*)d_in[8],
                *m2 = (const float*)d_in[9], *v2 = (const float*)d_in[10];
    const float* w3 = (const float*)d_in[11];
    const float *g3 = (const float*)d_in[12], *b3 = (const float*)d_in[13],
                *m3 = (const float*)d_in[14], *v3 = (const float*)d_in[15];
    const float* w4 = (const float*)d_in[16];
    const float *g4 = (const float*)d_in[17], *b4 = (const float*)d_in[18],
                *m4 = (const float*)d_in[19], *v4 = (const float*)d_in[20];
    const float* wg = (const float*)d_in[21];
    const float *gg = (const float*)d_in[22], *bg = (const float*)d_in[23],
                *mg = (const float*)d_in[24], *vg = (const float*)d_in[25];

    // workspace layout
    float* ws   = (float*)d_ws;
    float* xcat = ws;                                    // 8*2048*512
    float* xT   = xcat + (size_t)B * N * 512;            // 8*128*2048
    float* xx   = xT + (size_t)B * 128 * N;              // 8*2048
    int*   idx  = (int*)(xx + B * N);                    // 8*2048*20
    unsigned short* wf1h = (unsigned short*)(idx + (size_t)B * N * K);
    unsigned short* wf1l = wf1h + 64 * 32;
    unsigned short* wf2h = wf1l + 64 * 32;
    unsigned short* wf2l = wf2h + 64 * 128;
    unsigned short* wf3h = wf2l + 64 * 128;
    unsigned short* wf3l = wf3h + 128 * 128;
    unsigned short* wf4h = wf3l + 128 * 128;
    unsigned short* wf4l = wf4h + 256 * 256;
    unsigned short* wfgh = wf4l + 256 * 256;
    unsigned short* wfgl = wfgh + 512 * 512;
    unsigned int* keys  = (unsigned int*)(wfgl + 512 * 512);

    // pack weight fragments (bf16 hi/lo)
    wfrag_kernel<<<(64 * 32 + 255) / 256, 256, 0, stream>>>(w1, 64, 6, 32, wf1h, wf1l);
    wfrag_kernel<<<(64 * 128 + 255) / 256, 256, 0, stream>>>(w2, 64, 128, 128, wf2h, wf2l);
    wfrag_kernel<<<(128 * 128 + 255) / 256, 256, 0, stream>>>(w3, 128, 128, 128, wf3h, wf3l);
    wfrag_kernel<<<(256 * 256 + 255) / 256, 256, 0, stream>>>(w4, 256, 256, 256, wf4h, wf4l);
    wfrag_kernel<<<(512 * 512 + 255) / 256, 256, 0, stream>>>(wg, 512, 512, 512, wfgh, wfgl);

    // ---- layer 1: C=3 -> 64, out offset 0
    transpose_feat_kernel<<<(B * 3 * N + 255) / 256, 256, 0, stream>>>(pts, 3, 3, xT);
    sumsq_kernel<<<(B * N + 255) / 256, 256, 0, stream>>>(xT, 3, xx);
    dist_topk_kernel<<<B * (N / 4), 256, 0, stream>>>(xT, xx, 3, idx);
    edgeconv_mfma<3, 64, 8, 4, 1><<<B * (N / 8), 256, 0, stream>>>(pts, 3, idx, wf1h, wf1l, g1, b1, m1, v1, xcat + 0);

    // ---- layer 2: 64 -> 64, out offset 64
    transpose_feat_kernel<<<(B * 64 * N + 255) / 256, 256, 0, stream>>>(xcat + 0, 512, 64, xT);
    sumsq_kernel<<<(B * N + 255) / 256, 256, 0, stream>>>(xT, 64, xx);
    dist_topk_kernel<<<B * (N / 4), 256, 0, stream>>>(xT, xx, 64, idx);
    edgeconv_mfma<64, 64, 4, 4, 1><<<B * (N / 4), 256, 0, stream>>>(xcat + 0, 512, idx, wf2h, wf2l, g2, b2, m2, v2, xcat + 64);

    // ---- layer 3: 64 -> 128, out offset 128
    transpose_feat_kernel<<<(B * 64 * N + 255) / 256, 256, 0, stream>>>(xcat + 64, 512, 64, xT);
    sumsq_kernel<<<(B * N + 255) / 256, 256, 0, stream>>>(xT, 64, xx);
    dist_topk_kernel<<<B * (N / 4), 256, 0, stream>>>(xT, xx, 64, idx);
    edgeconv_mfma<64, 128, 4, 8, 1><<<B * (N / 4), 512, 0, stream>>>(xcat + 64, 512, idx, wf3h, wf3l, g3, b3, m3, v3, xcat + 128);

    // ---- layer 4: 128 -> 256, out offset 256 (K-chunked: NKC=2)
    transpose_feat_kernel<<<(B * 128 * N + 255) / 256, 256, 0, stream>>>(xcat + 128, 512, 128, xT);
    sumsq_kernel<<<(B * N + 255) / 256, 256, 0, stream>>>(xT, 128, xx);
    dist_topk_kernel<<<B * (N / 4), 256, 0, stream>>>(xT, xx, 128, idx);
    edgeconv_mfma<128, 256, 4, 8, 2><<<B * (N / 4), 512, 0, stream>>>(xcat + 128, 512, idx, wf4h, wf4l, g4, b4, m4, v4, xcat + 256);

    // ---- global layer + max over N
    hipMemsetAsync(keys, 0, (size_t)B * 512 * sizeof(unsigned int), stream);
    global_mfma<<<B * 32, 256, 0, stream>>>(xcat, wfgh, wfgl, gg, bg, mg, vg, keys);
    decode_kernel<<<(B * 512 + 255) / 256, 256, 0, stream>>>(keys, (float*)d_out);
}

// Round 5
// 1171.807 us; speedup vs baseline: 2.8976x; 1.0021x over previous
//
#include <hip/hip_runtime.h>
#include <hip/hip_bf16.h>

#define EPS 1e-5f

typedef __attribute__((ext_vector_type(8))) short bf16x8;
typedef __attribute__((ext_vector_type(4))) float f32x4;

// ---------------------------------------------------------------- utilities
__device__ __forceinline__ unsigned int fkey(float f) {
    unsigned int b = __float_as_uint(f);
    return (b & 0x80000000u) ? ~b : (b | 0x80000000u);
}
__device__ __forceinline__ float funkey(unsigned int k) {
    unsigned int b = (k & 0x80000000u) ? (k & 0x7fffffffu) : ~k;
    return __uint_as_float(b);
}
__device__ __forceinline__ unsigned short f2bu(float f) {
    union { __hip_bfloat16 h; unsigned short u; } cv;
    cv.h = __float2bfloat16(f);
    return cv.u;
}
__device__ __forceinline__ float bu2f(unsigned short u) {
    return __uint_as_float(((unsigned int)u) << 16);
}
__device__ __forceinline__ void hilo(float v, unsigned short& h, unsigned short& l) {
    h = f2bu(v);
    l = f2bu(v - bu2f(h));
}

// ------------------------------------------------------------ weight fragment packing (hi+lo planes)
__global__ void wfrag_kernel(const float* __restrict__ W, int CO, int C2, int C2P,
                             unsigned short* __restrict__ Fh, unsigned short* __restrict__ Fl) {
    int id = blockIdx.x * 256 + threadIdx.x;
    int total = CO * C2P;
    if (id >= total) return;
    int j = id & 7, lane = (id >> 3) & 63, t = id >> 9;
    int KS = C2P >> 5;
    int ks = t % KS, ot = t / KS;
    int o = ot * 16 + (lane & 15);
    int c = ks * 32 + ((lane >> 4) << 3) + j;
    float v = (c < C2) ? W[o * C2 + c] : 0.f;
    unsigned short h, l;
    hilo(v, h, l);
    Fh[id] = h;
    Fl[id] = l;
}

// ------------------------------------------------------------ transpose feat: xT[b][c][m]
__global__ void transpose_feat_kernel(const float* __restrict__ feat, int fstride, int C,
                                      float* __restrict__ xT) {
    const int N = 2048;
    int id = blockIdx.x * 256 + threadIdx.x;
    if (id >= 8 * C * N) return;
    int m = id & 2047;
    int bc = id >> 11;
    int c = bc % C, b = bc / C;
    xT[id] = feat[((size_t)b * N + m) * fstride + c];
}

// ------------------------------------------------------------ xx[b][n] = sum_c x^2
__global__ void sumsq_kernel(const float* __restrict__ xT, int C, float* __restrict__ xx) {
    const int N = 2048;
    int id = blockIdx.x * 256 + threadIdx.x;
    if (id >= 8 * N) return;
    int b = id >> 11, n = id & 2047;
    const float* p = xT + (size_t)b * C * N + n;
    float s = 0.f;
    for (int c = 0; c < C; ++c) { float v = p[(size_t)c * N]; s = fmaf(v, v, s); }
    xx[id] = s;
}

// ------------------------------------------------------------ distance tile + wave-local top-20 (u32 keys, exact ties)
__global__ void dist_topk_kernel(const float* __restrict__ xT, const float* __restrict__ xx,
                                 int C, int* __restrict__ idxOut) {
    const int N = 2048, TM = 4;
    int b  = blockIdx.x >> 9;
    int n0 = (blockIdx.x & 511) * TM;
    int tid = threadIdx.x;
    __shared__ float dist[TM][N];

    const float* xTb = xT + (size_t)b * C * N;

    float acc[TM][8];
#pragma unroll
    for (int r = 0; r < TM; ++r)
#pragma unroll
        for (int i = 0; i < 8; ++i) acc[r][i] = 0.f;

#pragma unroll 2
    for (int c = 0; c < C; ++c) {
        const float* row = xTb + (size_t)c * N;
        float4 c0 = *(const float4*)(row + 4 * tid);
        float4 c1 = *(const float4*)(row + 1024 + 4 * tid);
        float q[TM];
#pragma unroll
        for (int r = 0; r < TM; ++r) q[r] = row[n0 + r];
#pragma unroll
        for (int r = 0; r < TM; ++r) {
            acc[r][0] = fmaf(q[r], c0.x, acc[r][0]);
            acc[r][1] = fmaf(q[r], c0.y, acc[r][1]);
            acc[r][2] = fmaf(q[r], c0.z, acc[r][2]);
            acc[r][3] = fmaf(q[r], c0.w, acc[r][3]);
            acc[r][4] = fmaf(q[r], c1.x, acc[r][4]);
            acc[r][5] = fmaf(q[r], c1.y, acc[r][5]);
            acc[r][6] = fmaf(q[r], c1.z, acc[r][6]);
            acc[r][7] = fmaf(q[r], c1.w, acc[r][7]);
        }
    }
    {
        const float* xxb = xx + (size_t)b * N;
        float4 x0 = *(const float4*)(xxb + 4 * tid);
        float4 x1 = *(const float4*)(xxb + 1024 + 4 * tid);
        float xq[TM];
#pragma unroll
        for (int r = 0; r < TM; ++r) xq[r] = xxb[n0 + r];
#pragma unroll
        for (int r = 0; r < TM; ++r) {
            float4 d0, d1;
            d0.x = 2.f * acc[r][0] - xq[r] - x0.x;
            d0.y = 2.f * acc[r][1] - xq[r] - x0.y;
            d0.z = 2.f * acc[r][2] - xq[r] - x0.z;
            d0.w = 2.f * acc[r][3] - xq[r] - x0.w;
            d1.x = 2.f * acc[r][4] - xq[r] - x1.x;
            d1.y = 2.f * acc[r][5] - xq[r] - x1.y;
            d1.z = 2.f * acc[r][6] - xq[r] - x1.z;
            d1.w = 2.f * acc[r][7] - xq[r] - x1.w;
            *(float4*)&dist[r][4 * tid] = d0;
            *(float4*)&dist[r][1024 + 4 * tid] = d1;
        }
    }
    __syncthreads();

    // -------- phase B: wave-local top-20 on u32 monotone keys, exact stable tie-break
    int lane = tid & 63;
    int r = tid >> 6;
    unsigned int key[8][4];
#pragma unroll
    for (int j = 0; j < 8; ++j) {
        float4 v = *(const float4*)&dist[r][j * 256 + 4 * lane];
        key[j][0] = fkey(v.x);
        key[j][1] = fkey(v.y);
        key[j][2] = fkey(v.z);
        key[j][3] = fkey(v.w);
    }
    int resm = 0;
    for (int k = 0; k < 20; ++k) {
        // 1) global max value
        unsigned int gm = 0;
#pragma unroll
        for (int j = 0; j < 8; ++j) {
            unsigned int a0 = key[j][0] > key[j][1] ? key[j][0] : key[j][1];
            unsigned int a1 = key[j][2] > key[j][3] ? key[j][2] : key[j][3];
            unsigned int a  = a0 > a1 ? a0 : a1;
            gm = gm > a ? gm : a;
        }
#pragma unroll
        for (int s = 1; s < 64; s <<= 1) {
            unsigned int o = (unsigned int)__shfl_xor((int)gm, s);
            gm = gm > o ? gm : o;
        }
        // 2) global min index among elements equal to gm
        unsigned int midx = 0xFFFFFFFFu;
#pragma unroll
        for (int j = 0; j < 8; ++j)
#pragma unroll
            for (int i = 0; i < 4; ++i) {
                unsigned int m = (unsigned int)(j * 256 + 4 * lane + i);
                unsigned int cand = (key[j][i] == gm) ? m : 0xFFFFFFFFu;
                midx = midx < cand ? midx : cand;
            }
#pragma unroll
        for (int s = 1; s < 64; s <<= 1) {
            unsigned int o = (unsigned int)__shfl_xor((int)midx, s);
            midx = midx < o ? midx : o;
        }
        // 3) purge exactly that element (0 is unreachable for finite fkeys)
#pragma unroll
        for (int j = 0; j < 8; ++j)
#pragma unroll
            for (int i = 0; i < 4; ++i) {
                unsigned int m = (unsigned int)(j * 256 + 4 * lane + i);
                if (m == midx) key[j][i] = 0u;
            }
        if (lane == k) resm = (int)midx;
    }
    if (lane < 20) idxOut[((size_t)b * N + n0 + r) * 20 + lane] = resm;
}

// ------------------------------------------------------------ MFMA edgeconv, hi/lo split (3 MFMA per product)
template <int CI, int CO, int TN, int WAVES, int NKC>
__global__ __launch_bounds__(WAVES * 64) void
edgeconv_mfma(const float* __restrict__ feat, int fs, const int* __restrict__ idx,
              const unsigned short* __restrict__ Wh, const unsigned short* __restrict__ Wl,
              const float* __restrict__ gp, const float* __restrict__ bp,
              const float* __restrict__ mp, const float* __restrict__ vp,
              float* __restrict__ outBase) {
    constexpr int N = 2048, K = 20;
    constexpr int C2 = 2 * CI;
    constexpr int C2P = (C2 < 32) ? 32 : C2;
    constexpr int KS = C2P / 32;
    constexpr int KSC = KS / NKC;
    constexpr int CCOLS = KSC * 32;
    constexpr int CHB = CCOLS * 2;
    constexpr int OT = CO / 16;
    constexpr int OTW = OT / WAVES;
    constexpr int M = TN * K;
    constexpr int MT = M / 16;
    constexpr int NB = N / TN;
    constexpr int CH = CCOLS / 8;
    constexpr int SWZ = (CHB >= 128) ? 7 : (CHB / 16 - 1);
    constexpr int THREADS = WAVES * 64;

    int b  = blockIdx.x / NB;
    int n0 = (blockIdx.x % NB) * TN;
    int tid = threadIdx.x;
    int lane = tid & 63, wv = tid >> 6;

    __shared__ float ctr[TN][CI];
    __shared__ int nb[M];
    __shared__ __align__(16) unsigned char Eh[M * CHB];
    __shared__ __align__(16) unsigned char El[M * CHB];

    for (int e = tid; e < TN * CI; e += THREADS) {
        int ln = e / CI, c = e % CI;
        ctr[ln][c] = feat[((size_t)b * N + n0 + ln) * fs + c];
    }
    for (int e = tid; e < M; e += THREADS) {
        int k = e / TN, ln = e % TN;
        nb[e] = idx[((size_t)b * N + n0 + ln) * K + k];
    }
    __syncthreads();

    f32x4 acc[MT][OTW];
#pragma unroll
    for (int mt = 0; mt < MT; ++mt)
#pragma unroll
        for (int ot = 0; ot < OTW; ++ot)
#pragma unroll
            for (int rr = 0; rr < 4; ++rr) acc[mt][ot][rr] = 0.f;

    for (int kc = 0; kc < NKC; ++kc) {
        if (kc) __syncthreads();
        for (int e = tid; e < M * CH; e += THREADS) {
            int mrow = e / CH, ch = e - mrow * CH;
            int c0 = kc * CCOLS + ch * 8;
            int ln = mrow % TN;
            float v[8];
            if constexpr (CI >= 8) {
                if (c0 < CI) {
#pragma unroll
                    for (int j = 0; j < 8; ++j) v[j] = ctr[ln][c0 + j];
                } else {
                    int c1 = c0 - CI;
                    const float* nrow = feat + ((size_t)b * N + nb[mrow]) * fs + c1;
                    float4 a  = *(const float4*)nrow;
                    float4 b4 = *(const float4*)(nrow + 4);
                    v[0] = a.x  - ctr[ln][c1 + 0];
                    v[1] = a.y  - ctr[ln][c1 + 1];
                    v[2] = a.z  - ctr[ln][c1 + 2];
                    v[3] = a.w  - ctr[ln][c1 + 3];
                    v[4] = b4.x - ctr[ln][c1 + 4];
                    v[5] = b4.y - ctr[ln][c1 + 5];
                    v[6] = b4.z - ctr[ln][c1 + 6];
                    v[7] = b4.w - ctr[ln][c1 + 7];
                }
            } else {
                if (c0 == 0) {
                    const float* nrow = feat + ((size_t)b * N + nb[mrow]) * fs;
                    v[0] = ctr[ln][0]; v[1] = ctr[ln][1]; v[2] = ctr[ln][2];
                    v[3] = nrow[0] - ctr[ln][0];
                    v[4] = nrow[1] - ctr[ln][1];
                    v[5] = nrow[2] - ctr[ln][2];
                    v[6] = 0.f; v[7] = 0.f;
                } else {
#pragma unroll
                    for (int j = 0; j < 8; ++j) v[j] = 0.f;
                }
            }
            union { unsigned short u[8]; uint4 v4; } th, tl;
#pragma unroll
            for (int j = 0; j < 8; ++j) hilo(v[j], th.u[j], tl.u[j]);
            int off = mrow * CHB + ((ch * 16) ^ ((mrow & SWZ) << 4));
            *(uint4*)&Eh[off] = th.v4;
            *(uint4*)&El[off] = tl.v4;
        }
        __syncthreads();

        bf16x8 Bh[OTW][KSC], Bl[OTW][KSC];
#pragma unroll
        for (int ot = 0; ot < OTW; ++ot)
#pragma unroll
            for (int ksc = 0; ksc < KSC; ++ksc) {
                size_t fi = (size_t)((((wv * OTW + ot) * KS + kc * KSC + ksc) * 64 + lane)) << 3;
                Bh[ot][ksc] = *(const bf16x8*)(Wh + fi);
                Bl[ot][ksc] = *(const bf16x8*)(Wl + fi);
            }

#pragma unroll
        for (int mt = 0; mt < MT; ++mt) {
            int r0 = mt * 16 + (lane & 15);
            int cb = (lane >> 4) << 4;
            bf16x8 Ah[KSC], Al[KSC];
#pragma unroll
            for (int ksc = 0; ksc < KSC; ++ksc) {
                int off = r0 * CHB + (((ksc << 6) + cb) ^ ((r0 & SWZ) << 4));
                Ah[ksc] = *(const bf16x8*)&Eh[off];
                Al[ksc] = *(const bf16x8*)&El[off];
            }
#pragma unroll
            for (int ksc = 0; ksc < KSC; ++ksc)
#pragma unroll
                for (int ot = 0; ot < OTW; ++ot) {
                    acc[mt][ot] = __builtin_amdgcn_mfma_f32_16x16x32_bf16(Al[ksc], Bh[ot][ksc], acc[mt][ot], 0, 0, 0);
                    acc[mt][ot] = __builtin_amdgcn_mfma_f32_16x16x32_bf16(Ah[ksc], Bl[ot][ksc], acc[mt][ot], 0, 0, 0);
                    acc[mt][ot] = __builtin_amdgcn_mfma_f32_16x16x32_bf16(Ah[ksc], Bh[ot][ksc], acc[mt][ot], 0, 0, 0);
                }
        }
    }

#pragma unroll
    for (int ot = 0; ot < OTW; ++ot) {
        f32x4 v;
#pragma unroll
        for (int rr = 0; rr < 4; ++rr) {
            float m = acc[0][ot][rr];
#pragma unroll
            for (int mt = 1; mt < MT; ++mt) m = fmaxf(m, acc[mt][ot][rr]);
            if constexpr (TN == 4) m = fmaxf(m, __shfl_xor(m, 16));
            m = fmaxf(m, __shfl_xor(m, 32));
            v[rr] = m;
        }
        int o = (wv * OTW + ot) * 16 + (lane & 15);
        float s  = gp[o] * rsqrtf(vp[o] + EPS);
        float sh = bp[o] - mp[o] * s;
        bool valid = (TN == 8) ? (lane < 32) : (lane < 16);
        if (valid) {
            int lnb = (TN == 8) ? ((lane >> 4) << 2) : 0;
#pragma unroll
            for (int rr = 0; rr < 4; ++rr) {
                float h = fmaf(v[rr], s, sh);
                h = h > 0.f ? h : 0.2f * h;
                outBase[((size_t)b * N + n0 + lnb + rr) * 512 + o] = h;
            }
        }
    }
}

// ------------------------------------------------------------ global 512x512 MFMA (hi/lo) + BN+LReLU + max over N
__global__ __launch_bounds__(256) void
global_mfma(const float* __restrict__ xcat,
            const unsigned short* __restrict__ Wh, const unsigned short* __restrict__ Wl,
            const float* __restrict__ gg, const float* __restrict__ bg,
            const float* __restrict__ mg, const float* __restrict__ vg,
            unsigned int* __restrict__ keys) {
    const int N = 2048, CV = 512;
    int b  = blockIdx.x >> 5;
    int n0 = (blockIdx.x & 31) * 64;
    int tid = threadIdx.x, lane = tid & 63, wv = tid >> 6;

    f32x4 runmax[8];
#pragma unroll
    for (int ot = 0; ot < 8; ++ot)
#pragma unroll
        for (int rr = 0; rr < 4; ++rr) runmax[ot][rr] = -INFINITY;

    for (int mt = 0; mt < 4; ++mt) {
        int rown = n0 + mt * 16 + (lane & 15);
        const float* arow = xcat + ((size_t)b * N + rown) * CV + ((lane >> 4) << 3);
        bf16x8 Ah[16], Al[16];
#pragma unroll
        for (int ks = 0; ks < 16; ++ks) {
            float4 a  = *(const float4*)(arow + ks * 32);
            float4 b4 = *(const float4*)(arow + ks * 32 + 4);
            union { unsigned short u[8]; bf16x8 v; } ch, cl;
            hilo(a.x,  ch.u[0], cl.u[0]);
            hilo(a.y,  ch.u[1], cl.u[1]);
            hilo(a.z,  ch.u[2], cl.u[2]);
            hilo(a.w,  ch.u[3], cl.u[3]);
            hilo(b4.x, ch.u[4], cl.u[4]);
            hilo(b4.y, ch.u[5], cl.u[5]);
            hilo(b4.z, ch.u[6], cl.u[6]);
            hilo(b4.w, ch.u[7], cl.u[7]);
            Ah[ks] = ch.v; Al[ks] = cl.v;
        }
#pragma unroll
        for (int ot = 0; ot < 8; ++ot) {
            f32x4 acc;
#pragma unroll
            for (int rr = 0; rr < 4; ++rr) acc[rr] = 0.f;
#pragma unroll
            for (int ks = 0; ks < 16; ++ks) {
                size_t fi = (size_t)((((wv * 8 + ot) * 16 + ks) * 64 + lane)) << 3;
                bf16x8 Bh = *(const bf16x8*)(Wh + fi);
                bf16x8 Bl = *(const bf16x8*)(Wl + fi);
                acc = __builtin_amdgcn_mfma_f32_16x16x32_bf16(Al[ks], Bh, acc, 0, 0, 0);
                acc = __builtin_amdgcn_mfma_f32_16x16x32_bf16(Ah[ks], Bl, acc, 0, 0, 0);
                acc = __builtin_amdgcn_mfma_f32_16x16x32_bf16(Ah[ks], Bh, acc, 0, 0, 0);
            }
#pragma unroll
            for (int rr = 0; rr < 4; ++rr) runmax[ot][rr] = fmaxf(runmax[ot][rr], acc[rr]);
        }
    }
#pragma unroll
    for (int ot = 0; ot < 8; ++ot) {
        f32x4 v = runmax[ot];
#pragma unroll
        for (int rr = 0; rr < 4; ++rr) {
            v[rr] = fmaxf(v[rr], __shfl_xor(v[rr], 16));
            v[rr] = fmaxf(v[rr], __shfl_xor(v[rr], 32));
        }
        int o = wv * 128 + ot * 16 + (lane & 15);
        float s  = gg[o] * rsqrtf(vg[o] + EPS);
        float sh = bg[o] - mg[o] * s;
        if (lane < 16) {
            float hm = -INFINITY;
#pragma unroll
            for (int rr = 0; rr < 4; ++rr) {
                float h = fmaf(v[rr], s, sh);
                h = h > 0.f ? h : 0.2f * h;
                hm = fmaxf(hm, h);
            }
            atomicMax(&keys[b * 512 + o], fkey(hm));
        }
    }
}

__global__ void decode_kernel(const unsigned int* __restrict__ keys, float* __restrict__ out) {
    int id = blockIdx.x * 256 + threadIdx.x;
    if (id < 8 * 512) out[id] = funkey(keys[id]);
}

// ---------------------------------------------------------------- launcher
extern "C" void kernel_launch(void* const* d_in, const int* in_sizes, int n_in,
                              void* d_out, int out_size, void* d_ws, size_t ws_size,
                              hipStream_t stream) {
    const int B = 8, N = 2048, K = 20;
    const float* pts = (const float*)d_in[0];
    const float* w1 = (const float*)d_in[1];
    const float *g1 = (const float*)d_in[2], *b1 = (const float*)d_in[3],
                *m1 = (const float*)d_in[4], *v1 = (const float*)d_in[5];
    const float* w2 = (const float*)d_in[6];
    const float *g2 = (const float*)d_in[7], *b2 = (const float*)d_in[8],
                *m2 = (const float*)d_in[9], *v2 = (const float*)d_in[10];
    const float* w3 = (const float*)d_in[11];
    const float *g3 = (const float*)d_in[12], *b3 = (const float*)d_in[13],
                *m3 = (const float*)d_in[14], *v3 = (const float*)d_in[15];
    const float* w4 = (const float*)d_in[16];
    const float *g4 = (const float*)d_in[17], *b4 = (const float*)d_in[18],
                *m4 = (const float*)d_in[19], *v4 = (const float*)d_in[20];
    const float* wg = (const float*)d_in[21];
    const float *gg = (const float*)d_in[22], *bg = (const float*)d_in[23],
                *mg = (const float*)d_in[24], *vg = (const float*)d_in[25];

    // workspace layout
    float* ws   = (float*)d_ws;
    float* xcat = ws;                                    // 8*2048*512
    float* xT   = xcat + (size_t)B * N * 512;            // 8*128*2048
    float* xx   = xT + (size_t)B * 128 * N;              // 8*2048
    int*   idx  = (int*)(xx + B * N);                    // 8*2048*20
    unsigned short* wf1h = (unsigned short*)(idx + (size_t)B * N * K);
    unsigned short* wf1l = wf1h + 64 * 32;
    unsigned short* wf2h = wf1l + 64 * 32;
    unsigned short* wf2l = wf2h + 64 * 128;
    unsigned short* wf3h = wf2l + 64 * 128;
    unsigned short* wf3l = wf3h + 128 * 128;
    unsigned short* wf4h = wf3l + 128 * 128;
    unsigned short* wf4l = wf4h + 256 * 256;
    unsigned short* wfgh = wf4l + 256 * 256;
    unsigned short* wfgl = wfgh + 512 * 512;
    unsigned int* keys  = (unsigned int*)(wfgl + 512 * 512);

    // pack weight fragments (bf16 hi/lo)
    wfrag_kernel<<<(64 * 32 + 255) / 256, 256, 0, stream>>>(w1, 64, 6, 32, wf1h, wf1l);
    wfrag_kernel<<<(64 * 128 + 255) / 256, 256, 0, stream>>>(w2, 64, 128, 128, wf2h, wf2l);
    wfrag_kernel<<<(128 * 128 + 255) / 256, 256, 0, stream>>>(w3, 128, 128, 128, wf3h, wf3l);
    wfrag_kernel<<<(256 * 256 + 255) / 256, 256, 0, stream>>>(w4, 256, 256, 256, wf4h, wf4l);
    wfrag_kernel<<<(512 * 512 + 255) / 256, 256, 0, stream>>>(wg, 512, 512, 512, wfgh, wfgl);

    // ---- layer 1: C=3 -> 64, out offset 0
    transpose_feat_kernel<<<(B * 3 * N + 255) / 256, 256, 0, stream>>>(pts, 3, 3, xT);
    sumsq_kernel<<<(B * N + 255) / 256, 256, 0, stream>>>(xT, 3, xx);
    dist_topk_kernel<<<B * (N / 4), 256, 0, stream>>>(xT, xx, 3, idx);
    edgeconv_mfma<3, 64, 8, 4, 1><<<B * (N / 8), 256, 0, stream>>>(pts, 3, idx, wf1h, wf1l, g1, b1, m1, v1, xcat + 0);

    // ---- layer 2: 64 -> 64, out offset 64
    transpose_feat_kernel<<<(B * 64 * N + 255) / 256, 256, 0, stream>>>(xcat + 0, 512, 64, xT);
    sumsq_kernel<<<(B * N + 255) / 256, 256, 0, stream>>>(xT, 64, xx);
    dist_topk_kernel<<<B * (N / 4), 256, 0, stream>>>(xT, xx, 64, idx);
    edgeconv_mfma<64, 64, 4, 4, 1><<<B * (N / 4), 256, 0, stream>>>(xcat + 0, 512, idx, wf2h, wf2l, g2, b2, m2, v2, xcat + 64);

    // ---- layer 3: 64 -> 128, out offset 128
    transpose_feat_kernel<<<(B * 64 * N + 255) / 256, 256, 0, stream>>>(xcat + 64, 512, 64, xT);
    sumsq_kernel<<<(B * N + 255) / 256, 256, 0, stream>>>(xT, 64, xx);
    dist_topk_kernel<<<B * (N / 4), 256, 0, stream>>>(xT, xx, 64, idx);
    edgeconv_mfma<64, 128, 4, 8, 1><<<B * (N / 4), 512, 0, stream>>>(xcat + 64, 512, idx, wf3h, wf3l, g3, b3, m3, v3, xcat + 128);

    // ---- layer 4: 128 -> 256, out offset 256 (K-chunked: NKC=2)
    transpose_feat_kernel<<<(B * 128 * N + 255) / 256, 256, 0, stream>>>(xcat + 128, 512, 128, xT);
    sumsq_kernel<<<(B * N + 255) / 256, 256, 0, stream>>>(xT, 128, xx);
    dist_topk_kernel<<<B * (N / 4), 256, 0, stream>>>(xT, xx, 128, idx);
    edgeconv_mfma<128, 256, 4, 8, 2><<<B * (N / 4), 512, 0, stream>>>(xcat + 128, 512, idx, wf4h, wf4l, g4, b4, m4, v4, xcat + 256);

    // ---- global layer + max over N
    hipMemsetAsync(keys, 0, (size_t)B * 512 * sizeof(unsigned int), stream);
    global_mfma<<<B * 32, 256, 0, stream>>>(xcat, wfgh, wfgl, gg, bg, mg, vg, keys);
    decode_kernel<<<(B * 512 + 255) / 256, 256, 0, stream>>>(keys, (float*)d_out);
}

// Round 6
// 1119.140 us; speedup vs baseline: 3.0340x; 1.0471x over previous
//
#include <hip/hip_runtime.h>
#include <hip/hip_bf16.h>

#define EPS 1e-5f

typedef __attribute__((ext_vector_type(8))) short bf16x8;
typedef __attribute__((ext_vector_type(4))) float f32x4;

// ---------------------------------------------------------------- utilities
__device__ __forceinline__ unsigned int fkey(float f) {
    unsigned int b = __float_as_uint(f);
    return (b & 0x80000000u) ? ~b : (b | 0x80000000u);
}
__device__ __forceinline__ float funkey(unsigned int k) {
    unsigned int b = (k & 0x80000000u) ? (k & 0x7fffffffu) : ~k;
    return __uint_as_float(b);
}
__device__ __forceinline__ unsigned short f2bu(float f) {
    union { __hip_bfloat16 h; unsigned short u; } cv;
    cv.h = __float2bfloat16(f);
    return cv.u;
}
__device__ __forceinline__ float bu2f(unsigned short u) {
    return __uint_as_float(((unsigned int)u) << 16);
}
__device__ __forceinline__ void hilo(float v, unsigned short& h, unsigned short& l) {
    h = f2bu(v);
    l = f2bu(v - bu2f(h));
}

// ------------------------------------------------------------ weight fragment packing (hi+lo planes)
__global__ void wfrag_kernel(const float* __restrict__ W, int CO, int C2, int C2P,
                             unsigned short* __restrict__ Fh, unsigned short* __restrict__ Fl) {
    int id = blockIdx.x * 256 + threadIdx.x;
    int total = CO * C2P;
    if (id >= total) return;
    int j = id & 7, lane = (id >> 3) & 63, t = id >> 9;
    int KS = C2P >> 5;
    int ks = t % KS, ot = t / KS;
    int o = ot * 16 + (lane & 15);
    int c = ks * 32 + ((lane >> 4) << 3) + j;
    float v = (c < C2) ? W[o * C2 + c] : 0.f;
    unsigned short h, l;
    hilo(v, h, l);
    Fh[id] = h;
    Fl[id] = l;
}

// ------------------------------------------------------------ transpose feat: xT[b][c][m]
__global__ void transpose_feat_kernel(const float* __restrict__ feat, int fstride, int C,
                                      float* __restrict__ xT) {
    const int N = 2048;
    int id = blockIdx.x * 256 + threadIdx.x;
    if (id >= 8 * C * N) return;
    int m = id & 2047;
    int bc = id >> 11;
    int c = bc % C, b = bc / C;
    xT[id] = feat[((size_t)b * N + m) * fstride + c];
}

// ------------------------------------------------------------ xx[b][n] = sum_c x^2
__global__ void sumsq_kernel(const float* __restrict__ xT, int C, float* __restrict__ xx) {
    const int N = 2048;
    int id = blockIdx.x * 256 + threadIdx.x;
    if (id >= 8 * N) return;
    int b = id >> 11, n = id & 2047;
    const float* p = xT + (size_t)b * C * N + n;
    float s = 0.f;
    for (int c = 0; c < C; ++c) { float v = p[(size_t)c * N]; s = fmaf(v, v, s); }
    xx[id] = s;
}

// ------------------------------------------------------------ distance tile + wave-local top-20
// 512 threads, TM=8 rows/block; b = blockIdx&7 pins each batch to one XCD (L2-resident panel)
__global__ __launch_bounds__(512) void
dist_topk_kernel(const float* __restrict__ xT, const float* __restrict__ xx,
                 int C, int* __restrict__ idxOut) {
    const int N = 2048, TM = 8;
    int b  = blockIdx.x & 7;
    int n0 = (blockIdx.x >> 3) * TM;
    int tid = threadIdx.x;
    __shared__ float dist[TM][N];          // 64 KB

    const float* xTb = xT + (size_t)b * C * N;

    // ---------------- phase A: dot products, 8 rows x 4 cols per thread
    float acc[TM][4];
#pragma unroll
    for (int r = 0; r < TM; ++r)
#pragma unroll
        for (int i = 0; i < 4; ++i) acc[r][i] = 0.f;

#pragma unroll 2
    for (int c = 0; c < C; ++c) {
        const float* row = xTb + (size_t)c * N;
        float4 cv = *(const float4*)(row + 4 * tid);
        float q[TM];
#pragma unroll
        for (int r = 0; r < TM; ++r) q[r] = row[n0 + r];   // wave-uniform -> SMEM
#pragma unroll
        for (int r = 0; r < TM; ++r) {
            acc[r][0] = fmaf(q[r], cv.x, acc[r][0]);
            acc[r][1] = fmaf(q[r], cv.y, acc[r][1]);
            acc[r][2] = fmaf(q[r], cv.z, acc[r][2]);
            acc[r][3] = fmaf(q[r], cv.w, acc[r][3]);
        }
    }
    {
        const float* xxb = xx + (size_t)b * N;
        float4 xv = *(const float4*)(xxb + 4 * tid);
        float xq[TM];
#pragma unroll
        for (int r = 0; r < TM; ++r) xq[r] = xxb[n0 + r];
#pragma unroll
        for (int r = 0; r < TM; ++r) {
            float4 d;
            d.x = 2.f * acc[r][0] - xq[r] - xv.x;
            d.y = 2.f * acc[r][1] - xq[r] - xv.y;
            d.z = 2.f * acc[r][2] - xq[r] - xv.z;
            d.w = 2.f * acc[r][3] - xq[r] - xv.w;
            *(float4*)&dist[r][4 * tid] = d;
        }
    }
    __syncthreads();

    // ---------------- phase B: wave-local top-20 (u32 keys, exact stable ties), one row per wave
    int lane = tid & 63;
    int r = tid >> 6;
    unsigned int key[8][4];
#pragma unroll
    for (int j = 0; j < 8; ++j) {
        float4 v = *(const float4*)&dist[r][j * 256 + 4 * lane];
        key[j][0] = fkey(v.x);
        key[j][1] = fkey(v.y);
        key[j][2] = fkey(v.z);
        key[j][3] = fkey(v.w);
    }
    int resm = 0;
    for (int k = 0; k < 20; ++k) {
        unsigned int gm = 0;
#pragma unroll
        for (int j = 0; j < 8; ++j) {
            unsigned int a0 = key[j][0] > key[j][1] ? key[j][0] : key[j][1];
            unsigned int a1 = key[j][2] > key[j][3] ? key[j][2] : key[j][3];
            unsigned int a  = a0 > a1 ? a0 : a1;
            gm = gm > a ? gm : a;
        }
#pragma unroll
        for (int s = 1; s < 64; s <<= 1) {
            unsigned int o = (unsigned int)__shfl_xor((int)gm, s);
            gm = gm > o ? gm : o;
        }
        unsigned int midx = 0xFFFFFFFFu;
#pragma unroll
        for (int j = 0; j < 8; ++j)
#pragma unroll
            for (int i = 0; i < 4; ++i) {
                unsigned int m = (unsigned int)(j * 256 + 4 * lane + i);
                unsigned int cand = (key[j][i] == gm) ? m : 0xFFFFFFFFu;
                midx = midx < cand ? midx : cand;
            }
#pragma unroll
        for (int s = 1; s < 64; s <<= 1) {
            unsigned int o = (unsigned int)__shfl_xor((int)midx, s);
            midx = midx < o ? midx : o;
        }
#pragma unroll
        for (int j = 0; j < 8; ++j)
#pragma unroll
            for (int i = 0; i < 4; ++i) {
                unsigned int m = (unsigned int)(j * 256 + 4 * lane + i);
                if (m == midx) key[j][i] = 0u;
            }
        if (lane == k) resm = (int)midx;
    }
    if (lane < 20) idxOut[((size_t)b * N + n0 + r) * 20 + lane] = resm;
}

// ------------------------------------------------------------ MFMA edgeconv, hi/lo split (3 MFMA per product)
// b = blockIdx&7 pins batch -> XCD (4MB xcat panel ~= L2)
template <int CI, int CO, int TN, int WAVES, int NKC>
__global__ __launch_bounds__(WAVES * 64) void
edgeconv_mfma(const float* __restrict__ feat, int fs, const int* __restrict__ idx,
              const unsigned short* __restrict__ Wh, const unsigned short* __restrict__ Wl,
              const float* __restrict__ gp, const float* __restrict__ bp,
              const float* __restrict__ mp, const float* __restrict__ vp,
              float* __restrict__ outBase) {
    constexpr int N = 2048, K = 20;
    constexpr int C2 = 2 * CI;
    constexpr int C2P = (C2 < 32) ? 32 : C2;
    constexpr int KS = C2P / 32;
    constexpr int KSC = KS / NKC;
    constexpr int CCOLS = KSC * 32;
    constexpr int CHB = CCOLS * 2;
    constexpr int OT = CO / 16;
    constexpr int OTW = OT / WAVES;
    constexpr int M = TN * K;
    constexpr int MT = M / 16;
    constexpr int CH = CCOLS / 8;
    constexpr int SWZ = (CHB >= 128) ? 7 : (CHB / 16 - 1);
    constexpr int THREADS = WAVES * 64;

    int b  = blockIdx.x & 7;
    int n0 = (blockIdx.x >> 3) * TN;
    int tid = threadIdx.x;
    int lane = tid & 63, wv = tid >> 6;

    __shared__ float ctr[TN][CI];
    __shared__ int nb[M];
    __shared__ __align__(16) unsigned char Eh[M * CHB];
    __shared__ __align__(16) unsigned char El[M * CHB];

    for (int e = tid; e < TN * CI; e += THREADS) {
        int ln = e / CI, c = e % CI;
        ctr[ln][c] = feat[((size_t)b * N + n0 + ln) * fs + c];
    }
    for (int e = tid; e < M; e += THREADS) {
        int k = e / TN, ln = e % TN;
        nb[e] = idx[((size_t)b * N + n0 + ln) * K + k];
    }
    __syncthreads();

    f32x4 acc[MT][OTW];
#pragma unroll
    for (int mt = 0; mt < MT; ++mt)
#pragma unroll
        for (int ot = 0; ot < OTW; ++ot)
#pragma unroll
            for (int rr = 0; rr < 4; ++rr) acc[mt][ot][rr] = 0.f;

    for (int kc = 0; kc < NKC; ++kc) {
        if (kc) __syncthreads();
        for (int e = tid; e < M * CH; e += THREADS) {
            int mrow = e / CH, ch = e - mrow * CH;
            int c0 = kc * CCOLS + ch * 8;
            int ln = mrow % TN;
            float v[8];
            if constexpr (CI >= 8) {
                if (c0 < CI) {
#pragma unroll
                    for (int j = 0; j < 8; ++j) v[j] = ctr[ln][c0 + j];
                } else {
                    int c1 = c0 - CI;
                    const float* nrow = feat + ((size_t)b * N + nb[mrow]) * fs + c1;
                    float4 a  = *(const float4*)nrow;
                    float4 b4 = *(const float4*)(nrow + 4);
                    v[0] = a.x  - ctr[ln][c1 + 0];
                    v[1] = a.y  - ctr[ln][c1 + 1];
                    v[2] = a.z  - ctr[ln][c1 + 2];
                    v[3] = a.w  - ctr[ln][c1 + 3];
                    v[4] = b4.x - ctr[ln][c1 + 4];
                    v[5] = b4.y - ctr[ln][c1 + 5];
                    v[6] = b4.z - ctr[ln][c1 + 6];
                    v[7] = b4.w - ctr[ln][c1 + 7];
                }
            } else {
                if (c0 == 0) {
                    const float* nrow = feat + ((size_t)b * N + nb[mrow]) * fs;
                    v[0] = ctr[ln][0]; v[1] = ctr[ln][1]; v[2] = ctr[ln][2];
                    v[3] = nrow[0] - ctr[ln][0];
                    v[4] = nrow[1] - ctr[ln][1];
                    v[5] = nrow[2] - ctr[ln][2];
                    v[6] = 0.f; v[7] = 0.f;
                } else {
#pragma unroll
                    for (int j = 0; j < 8; ++j) v[j] = 0.f;
                }
            }
            union { unsigned short u[8]; uint4 v4; } th, tl;
#pragma unroll
            for (int j = 0; j < 8; ++j) hilo(v[j], th.u[j], tl.u[j]);
            int off = mrow * CHB + ((ch * 16) ^ ((mrow & SWZ) << 4));
            *(uint4*)&Eh[off] = th.v4;
            *(uint4*)&El[off] = tl.v4;
        }
        __syncthreads();

        bf16x8 Bh[OTW][KSC], Bl[OTW][KSC];
#pragma unroll
        for (int ot = 0; ot < OTW; ++ot)
#pragma unroll
            for (int ksc = 0; ksc < KSC; ++ksc) {
                size_t fi = (size_t)((((wv * OTW + ot) * KS + kc * KSC + ksc) * 64 + lane)) << 3;
                Bh[ot][ksc] = *(const bf16x8*)(Wh + fi);
                Bl[ot][ksc] = *(const bf16x8*)(Wl + fi);
            }

#pragma unroll
        for (int mt = 0; mt < MT; ++mt) {
            int r0 = mt * 16 + (lane & 15);
            int cb = (lane >> 4) << 4;
            bf16x8 Ah[KSC], Al[KSC];
#pragma unroll
            for (int ksc = 0; ksc < KSC; ++ksc) {
                int off = r0 * CHB + (((ksc << 6) + cb) ^ ((r0 & SWZ) << 4));
                Ah[ksc] = *(const bf16x8*)&Eh[off];
                Al[ksc] = *(const bf16x8*)&El[off];
            }
#pragma unroll
            for (int ksc = 0; ksc < KSC; ++ksc)
#pragma unroll
                for (int ot = 0; ot < OTW; ++ot) {
                    acc[mt][ot] = __builtin_amdgcn_mfma_f32_16x16x32_bf16(Al[ksc], Bh[ot][ksc], acc[mt][ot], 0, 0, 0);
                    acc[mt][ot] = __builtin_amdgcn_mfma_f32_16x16x32_bf16(Ah[ksc], Bl[ot][ksc], acc[mt][ot], 0, 0, 0);
                    acc[mt][ot] = __builtin_amdgcn_mfma_f32_16x16x32_bf16(Ah[ksc], Bh[ot][ksc], acc[mt][ot], 0, 0, 0);
                }
        }
    }

#pragma unroll
    for (int ot = 0; ot < OTW; ++ot) {
        f32x4 v;
#pragma unroll
        for (int rr = 0; rr < 4; ++rr) {
            float m = acc[0][ot][rr];
#pragma unroll
            for (int mt = 1; mt < MT; ++mt) m = fmaxf(m, acc[mt][ot][rr]);
            if constexpr (TN == 4) m = fmaxf(m, __shfl_xor(m, 16));
            m = fmaxf(m, __shfl_xor(m, 32));
            v[rr] = m;
        }
        int o = (wv * OTW + ot) * 16 + (lane & 15);
        float s  = gp[o] * rsqrtf(vp[o] + EPS);
        float sh = bp[o] - mp[o] * s;
        bool valid = (TN == 8) ? (lane < 32) : (lane < 16);
        if (valid) {
            int lnb = (TN == 8) ? ((lane >> 4) << 2) : 0;
#pragma unroll
            for (int rr = 0; rr < 4; ++rr) {
                float h = fmaf(v[rr], s, sh);
                h = h > 0.f ? h : 0.2f * h;
                outBase[((size_t)b * N + n0 + lnb + rr) * 512 + o] = h;
            }
        }
    }
}

// ------------------------------------------------------------ global 512x512 MFMA (hi/lo) + BN+LReLU + max over N
__global__ __launch_bounds__(256) void
global_mfma(const float* __restrict__ xcat,
            const unsigned short* __restrict__ Wh, const unsigned short* __restrict__ Wl,
            const float* __restrict__ gg, const float* __restrict__ bg,
            const float* __restrict__ mg, const float* __restrict__ vg,
            unsigned int* __restrict__ keys) {
    const int N = 2048, CV = 512;
    int b  = blockIdx.x & 7;
    int n0 = (blockIdx.x >> 3) * 64;
    int tid = threadIdx.x, lane = tid & 63, wv = tid >> 6;

    f32x4 runmax[8];
#pragma unroll
    for (int ot = 0; ot < 8; ++ot)
#pragma unroll
        for (int rr = 0; rr < 4; ++rr) runmax[ot][rr] = -INFINITY;

    for (int mt = 0; mt < 4; ++mt) {
        int rown = n0 + mt * 16 + (lane & 15);
        const float* arow = xcat + ((size_t)b * N + rown) * CV + ((lane >> 4) << 3);
        bf16x8 Ah[16], Al[16];
#pragma unroll
        for (int ks = 0; ks < 16; ++ks) {
            float4 a  = *(const float4*)(arow + ks * 32);
            float4 b4 = *(const float4*)(arow + ks * 32 + 4);
            union { unsigned short u[8]; bf16x8 v; } ch, cl;
            hilo(a.x,  ch.u[0], cl.u[0]);
            hilo(a.y,  ch.u[1], cl.u[1]);
            hilo(a.z,  ch.u[2], cl.u[2]);
            hilo(a.w,  ch.u[3], cl.u[3]);
            hilo(b4.x, ch.u[4], cl.u[4]);
            hilo(b4.y, ch.u[5], cl.u[5]);
            hilo(b4.z, ch.u[6], cl.u[6]);
            hilo(b4.w, ch.u[7], cl.u[7]);
            Ah[ks] = ch.v; Al[ks] = cl.v;
        }
#pragma unroll
        for (int ot = 0; ot < 8; ++ot) {
            f32x4 acc;
#pragma unroll
            for (int rr = 0; rr < 4; ++rr) acc[rr] = 0.f;
#pragma unroll
            for (int ks = 0; ks < 16; ++ks) {
                size_t fi = (size_t)((((wv * 8 + ot) * 16 + ks) * 64 + lane)) << 3;
                bf16x8 Bh = *(const bf16x8*)(Wh + fi);
                bf16x8 Bl = *(const bf16x8*)(Wl + fi);
                acc = __builtin_amdgcn_mfma_f32_16x16x32_bf16(Al[ks], Bh, acc, 0, 0, 0);
                acc = __builtin_amdgcn_mfma_f32_16x16x32_bf16(Ah[ks], Bl, acc, 0, 0, 0);
                acc = __builtin_amdgcn_mfma_f32_16x16x32_bf16(Ah[ks], Bh, acc, 0, 0, 0);
            }
#pragma unroll
            for (int rr = 0; rr < 4; ++rr) runmax[ot][rr] = fmaxf(runmax[ot][rr], acc[rr]);
        }
    }
#pragma unroll
    for (int ot = 0; ot < 8; ++ot) {
        f32x4 v = runmax[ot];
#pragma unroll
        for (int rr = 0; rr < 4; ++rr) {
            v[rr] = fmaxf(v[rr], __shfl_xor(v[rr], 16));
            v[rr] = fmaxf(v[rr], __shfl_xor(v[rr], 32));
        }
        int o = wv * 128 + ot * 16 + (lane & 15);
        float s  = gg[o] * rsqrtf(vg[o] + EPS);
        float sh = bg[o] - mg[o] * s;
        if (lane < 16) {
            float hm = -INFINITY;
#pragma unroll
            for (int rr = 0; rr < 4; ++rr) {
                float h = fmaf(v[rr], s, sh);
                h = h > 0.f ? h : 0.2f * h;
                hm = fmaxf(hm, h);
            }
            atomicMax(&keys[b * 512 + o], fkey(hm));
        }
    }
}

__global__ void decode_kernel(const unsigned int* __restrict__ keys, float* __restrict__ out) {
    int id = blockIdx.x * 256 + threadIdx.x;
    if (id < 8 * 512) out[id] = funkey(keys[id]);
}

// ---------------------------------------------------------------- launcher
extern "C" void kernel_launch(void* const* d_in, const int* in_sizes, int n_in,
                              void* d_out, int out_size, void* d_ws, size_t ws_size,
                              hipStream_t stream) {
    const int B = 8, N = 2048, K = 20;
    const float* pts = (const float*)d_in[0];
    const float* w1 = (const float*)d_in[1];
    const float *g1 = (const float*)d_in[2], *b1 = (const float*)d_in[3],
                *m1 = (const float*)d_in[4], *v1 = (const float*)d_in[5];
    const float* w2 = (const float*)d_in[6];
    const float *g2 = (const float*)d_in[7], *b2 = (const float*)d_in[8],
                *m2 = (const float*)d_in[9], *v2 = (const float*)d_in[10];
    const float* w3 = (const float*)d_in[11];
    const float *g3 = (const float*)d_in[12], *b3 = (const float*)d_in[13],
                *m3 = (const float*)d_in[14], *v3 = (const float*)d_in[15];
    const float* w4 = (const float*)d_in[16];
    const float *g4 = (const float*)d_in[17], *b4 = (const float*)d_in[18],
                *m4 = (const float*)d_in[19], *v4 = (const float*)d_in[20];
    const float* wg = (const float*)d_in[21];
    const float *gg = (const float*)d_in[22], *bg = (const float*)d_in[23],
                *mg = (const float*)d_in[24], *vg = (const float*)d_in[25];

    // workspace layout
    float* ws   = (float*)d_ws;
    float* xcat = ws;                                    // 8*2048*512
    float* xT   = xcat + (size_t)B * N * 512;            // 8*128*2048
    float* xx   = xT + (size_t)B * 128 * N;              // 8*2048
    int*   idx  = (int*)(xx + B * N);                    // 8*2048*20
    unsigned short* wf1h = (unsigned short*)(idx + (size_t)B * N * K);
    unsigned short* wf1l = wf1h + 64 * 32;
    unsigned short* wf2h = wf1l + 64 * 32;
    unsigned short* wf2l = wf2h + 64 * 128;
    unsigned short* wf3h = wf2l + 64 * 128;
    unsigned short* wf3l = wf3h + 128 * 128;
    unsigned short* wf4h = wf3l + 128 * 128;
    unsigned short* wf4l = wf4h + 256 * 256;
    unsigned short* wfgh = wf4l + 256 * 256;
    unsigned short* wfgl = wfgh + 512 * 512;
    unsigned int* keys  = (unsigned int*)(wfgl + 512 * 512);

    // pack weight fragments (bf16 hi/lo)
    wfrag_kernel<<<(64 * 32 + 255) / 256, 256, 0, stream>>>(w1, 64, 6, 32, wf1h, wf1l);
    wfrag_kernel<<<(64 * 128 + 255) / 256, 256, 0, stream>>>(w2, 64, 128, 128, wf2h, wf2l);
    wfrag_kernel<<<(128 * 128 + 255) / 256, 256, 0, stream>>>(w3, 128, 128, 128, wf3h, wf3l);
    wfrag_kernel<<<(256 * 256 + 255) / 256, 256, 0, stream>>>(w4, 256, 256, 256, wf4h, wf4l);
    wfrag_kernel<<<(512 * 512 + 255) / 256, 256, 0, stream>>>(wg, 512, 512, 512, wfgh, wfgl);

    // ---- layer 1: C=3 -> 64, out offset 0
    transpose_feat_kernel<<<(B * 3 * N + 255) / 256, 256, 0, stream>>>(pts, 3, 3, xT);
    sumsq_kernel<<<(B * N + 255) / 256, 256, 0, stream>>>(xT, 3, xx);
    dist_topk_kernel<<<B * (N / 8), 512, 0, stream>>>(xT, xx, 3, idx);
    edgeconv_mfma<3, 64, 8, 4, 1><<<B * (N / 8), 256, 0, stream>>>(pts, 3, idx, wf1h, wf1l, g1, b1, m1, v1, xcat + 0);

    // ---- layer 2: 64 -> 64, out offset 64
    transpose_feat_kernel<<<(B * 64 * N + 255) / 256, 256, 0, stream>>>(xcat + 0, 512, 64, xT);
    sumsq_kernel<<<(B * N + 255) / 256, 256, 0, stream>>>(xT, 64, xx);
    dist_topk_kernel<<<B * (N / 8), 512, 0, stream>>>(xT, xx, 64, idx);
    edgeconv_mfma<64, 64, 4, 4, 1><<<B * (N / 4), 256, 0, stream>>>(xcat + 0, 512, idx, wf2h, wf2l, g2, b2, m2, v2, xcat + 64);

    // ---- layer 3: 64 -> 128, out offset 128
    transpose_feat_kernel<<<(B * 64 * N + 255) / 256, 256, 0, stream>>>(xcat + 64, 512, 64, xT);
    sumsq_kernel<<<(B * N + 255) / 256, 256, 0, stream>>>(xT, 64, xx);
    dist_topk_kernel<<<B * (N / 8), 512, 0, stream>>>(xT, xx, 64, idx);
    edgeconv_mfma<64, 128, 4, 8, 1><<<B * (N / 4), 512, 0, stream>>>(xcat + 64, 512, idx, wf3h, wf3l, g3, b3, m3, v3, xcat + 128);

    // ---- layer 4: 128 -> 256, out offset 256 (K-chunked: NKC=2)
    transpose_feat_kernel<<<(B * 128 * N + 255) / 256, 256, 0, stream>>>(xcat + 128, 512, 128, xT);
    sumsq_kernel<<<(B * N + 255) / 256, 256, 0, stream>>>(xT, 128, xx);
    dist_topk_kernel<<<B * (N / 8), 512, 0, stream>>>(xT, xx, 128, idx);
    edgeconv_mfma<128, 256, 4, 8, 2><<<B * (N / 4), 512, 0, stream>>>(xcat + 128, 512, idx, wf4h, wf4l, g4, b4, m4, v4, xcat + 256);

    // ---- global layer + max over N
    hipMemsetAsync(keys, 0, (size_t)B * 512 * sizeof(unsigned int), stream);
    global_mfma<<<B * 32, 256, 0, stream>>>(xcat, wfgh, wfgl, gg, bg, mg, vg, keys);
    decode_kernel<<<(B * 512 + 255) / 256, 256, 0, stream>>>(keys, (float*)d_out);
}

// Round 7
// 959.613 us; speedup vs baseline: 3.5383x; 1.1662x over previous
//
#include <hip/hip_runtime.h>
#include <hip/hip_bf16.h>

#define EPS 1e-5f

typedef __attribute__((ext_vector_type(8))) short bf16x8;
typedef __attribute__((ext_vector_type(4))) float f32x4;

// ---------------------------------------------------------------- utilities
__device__ __forceinline__ unsigned int fkey(float f) {
    unsigned int b = __float_as_uint(f);
    return (b & 0x80000000u) ? ~b : (b | 0x80000000u);
}
__device__ __forceinline__ float funkey(unsigned int k) {
    unsigned int b = (k & 0x80000000u) ? (k & 0x7fffffffu) : ~k;
    return __uint_as_float(b);
}
__device__ __forceinline__ unsigned short f2bu(float f) {
    union { __hip_bfloat16 h; unsigned short u; } cv;
    cv.h = __float2bfloat16(f);
    return cv.u;
}
__device__ __forceinline__ float bu2f(unsigned short u) {
    return __uint_as_float(((unsigned int)u) << 16);
}
__device__ __forceinline__ void hilo(float v, unsigned short& h, unsigned short& l) {
    h = f2bu(v);
    l = f2bu(v - bu2f(h));
}

// ------------------------------------------------------------ weight fragment packing (hi+lo planes)
__global__ void wfrag_kernel(const float* __restrict__ W, int CO, int C2, int C2P,
                             unsigned short* __restrict__ Fh, unsigned short* __restrict__ Fl) {
    int id = blockIdx.x * 256 + threadIdx.x;
    int total = CO * C2P;
    if (id >= total) return;
    int j = id & 7, lane = (id >> 3) & 63, t = id >> 9;
    int KS = C2P >> 5;
    int ks = t % KS, ot = t / KS;
    int o = ot * 16 + (lane & 15);
    int c = ks * 32 + ((lane >> 4) << 3) + j;
    float v = (c < C2) ? W[o * C2 + c] : 0.f;
    unsigned short h, l;
    hilo(v, h, l);
    Fh[id] = h;
    Fl[id] = l;
}

// ------------------------------------------------------------ transpose feat: xT[b][c][m]
__global__ void transpose_feat_kernel(const float* __restrict__ feat, int fstride, int C,
                                      float* __restrict__ xT) {
    const int N = 2048;
    int id = blockIdx.x * 256 + threadIdx.x;
    if (id >= 8 * C * N) return;
    int m = id & 2047;
    int bc = id >> 11;
    int c = bc % C, b = bc / C;
    xT[id] = feat[((size_t)b * N + m) * fstride + c];
}

// ------------------------------------------------------------ xx[b][n] = sum_c x^2
__global__ void sumsq_kernel(const float* __restrict__ xT, int C, float* __restrict__ xx) {
    const int N = 2048;
    int id = blockIdx.x * 256 + threadIdx.x;
    if (id >= 8 * N) return;
    int b = id >> 11, n = id & 2047;
    const float* p = xT + (size_t)b * C * N + n;
    float s = 0.f;
    for (int c = 0; c < C; ++c) { float v = p[(size_t)c * N]; s = fmaf(v, v, s); }
    xx[id] = s;
}

// ------------------------------------------------------------ distance tile + wave-local top-20
// 512 threads, TM=8 rows/block; b = blockIdx&7 pins each batch to one XCD (L2-resident panel)
// phase B: exact f64 packed-key filter (value*4096 + (2047-m)) -- 4 ops/elem/round
__global__ __launch_bounds__(512) void
dist_topk_kernel(const float* __restrict__ xT, const float* __restrict__ xx,
                 int C, int* __restrict__ idxOut) {
    const int N = 2048, TM = 8;
    int b  = blockIdx.x & 7;
    int n0 = (blockIdx.x >> 3) * TM;
    int tid = threadIdx.x;
    __shared__ float dist[TM][N];          // 64 KB

    const float* xTb = xT + (size_t)b * C * N;

    // ---------------- phase A: dot products, 8 rows x 4 cols per thread
    float acc[TM][4];
#pragma unroll
    for (int r = 0; r < TM; ++r)
#pragma unroll
        for (int i = 0; i < 4; ++i) acc[r][i] = 0.f;

#pragma unroll 2
    for (int c = 0; c < C; ++c) {
        const float* row = xTb + (size_t)c * N;
        float4 cv = *(const float4*)(row + 4 * tid);
        float q[TM];
#pragma unroll
        for (int r = 0; r < TM; ++r) q[r] = row[n0 + r];   // wave-uniform
#pragma unroll
        for (int r = 0; r < TM; ++r) {
            acc[r][0] = fmaf(q[r], cv.x, acc[r][0]);
            acc[r][1] = fmaf(q[r], cv.y, acc[r][1]);
            acc[r][2] = fmaf(q[r], cv.z, acc[r][2]);
            acc[r][3] = fmaf(q[r], cv.w, acc[r][3]);
        }
    }
    {
        const float* xxb = xx + (size_t)b * N;
        float4 xv = *(const float4*)(xxb + 4 * tid);
        float xq[TM];
#pragma unroll
        for (int r = 0; r < TM; ++r) xq[r] = xxb[n0 + r];
#pragma unroll
        for (int r = 0; r < TM; ++r) {
            float4 d;
            d.x = 2.f * acc[r][0] - xq[r] - xv.x;
            d.y = 2.f * acc[r][1] - xq[r] - xv.y;
            d.z = 2.f * acc[r][2] - xq[r] - xv.z;
            d.w = 2.f * acc[r][3] - xq[r] - xv.w;
            *(float4*)&dist[r][4 * tid] = d;
        }
    }
    __syncthreads();

    // ---------------- phase B: one row per wave, f64 packed keys
    int lane = tid & 63;
    int r = tid >> 6;
    double key[8][4];
#pragma unroll
    for (int j = 0; j < 8; ++j) {
        float4 v = *(const float4*)&dist[r][j * 256 + 4 * lane];
        int m0 = j * 256 + 4 * lane;
        key[j][0] = (double)fkey(v.x) * 4096.0 + (double)(2047 - (m0 + 0));
        key[j][1] = (double)fkey(v.y) * 4096.0 + (double)(2047 - (m0 + 1));
        key[j][2] = (double)fkey(v.z) * 4096.0 + (double)(2047 - (m0 + 2));
        key[j][3] = (double)fkey(v.w) * 4096.0 + (double)(2047 - (m0 + 3));
    }
    double pkey = 1e300;
    int resm = 0;
    for (int k = 0; k < 20; ++k) {
        double bk = -1.0;
#pragma unroll
        for (int j = 0; j < 8; ++j)
#pragma unroll
            for (int i = 0; i < 4; ++i) {
                double kk = key[j][i];
                bk = fmax(bk, kk < pkey ? kk : -1.0);
            }
#pragma unroll
        for (int s = 1; s < 64; s <<= 1)
            bk = fmax(bk, __shfl_xor(bk, s));
        pkey = bk;
        int m = 2047 - (int)(((long long)bk) & 4095);
        if (lane == k) resm = m;
    }
    if (lane < 20) idxOut[((size_t)b * N + n0 + r) * 20 + lane] = resm;
}

// ------------------------------------------------------------ MFMA edgeconv, hi/lo split (3 MFMA per product)
template <int CI, int CO, int TN, int WAVES, int NKC>
__global__ __launch_bounds__(WAVES * 64) void
edgeconv_mfma(const float* __restrict__ feat, int fs, const int* __restrict__ idx,
              const unsigned short* __restrict__ Wh, const unsigned short* __restrict__ Wl,
              const float* __restrict__ gp, const float* __restrict__ bp,
              const float* __restrict__ mp, const float* __restrict__ vp,
              float* __restrict__ outBase) {
    constexpr int N = 2048, K = 20;
    constexpr int C2 = 2 * CI;
    constexpr int C2P = (C2 < 32) ? 32 : C2;
    constexpr int KS = C2P / 32;
    constexpr int KSC = KS / NKC;
    constexpr int CCOLS = KSC * 32;
    constexpr int CHB = CCOLS * 2;
    constexpr int OT = CO / 16;
    constexpr int OTW = OT / WAVES;
    constexpr int M = TN * K;
    constexpr int MT = M / 16;
    constexpr int CH = CCOLS / 8;
    constexpr int SWZ = (CHB >= 128) ? 7 : (CHB / 16 - 1);
    constexpr int THREADS = WAVES * 64;

    int b  = blockIdx.x & 7;
    int n0 = (blockIdx.x >> 3) * TN;
    int tid = threadIdx.x;
    int lane = tid & 63, wv = tid >> 6;

    __shared__ float ctr[TN][CI];
    __shared__ int nb[M];
    __shared__ __align__(16) unsigned char Eh[M * CHB];
    __shared__ __align__(16) unsigned char El[M * CHB];

    for (int e = tid; e < TN * CI; e += THREADS) {
        int ln = e / CI, c = e % CI;
        ctr[ln][c] = feat[((size_t)b * N + n0 + ln) * fs + c];
    }
    for (int e = tid; e < M; e += THREADS) {
        int k = e / TN, ln = e % TN;
        nb[e] = idx[((size_t)b * N + n0 + ln) * K + k];
    }
    __syncthreads();

    f32x4 acc[MT][OTW];
#pragma unroll
    for (int mt = 0; mt < MT; ++mt)
#pragma unroll
        for (int ot = 0; ot < OTW; ++ot)
#pragma unroll
            for (int rr = 0; rr < 4; ++rr) acc[mt][ot][rr] = 0.f;

    for (int kc = 0; kc < NKC; ++kc) {
        if (kc) __syncthreads();
        for (int e = tid; e < M * CH; e += THREADS) {
            int mrow = e / CH, ch = e - mrow * CH;
            int c0 = kc * CCOLS + ch * 8;
            int ln = mrow % TN;
            float v[8];
            if constexpr (CI >= 8) {
                if (c0 < CI) {
#pragma unroll
                    for (int j = 0; j < 8; ++j) v[j] = ctr[ln][c0 + j];
                } else {
                    int c1 = c0 - CI;
                    const float* nrow = feat + ((size_t)b * N + nb[mrow]) * fs + c1;
                    float4 a  = *(const float4*)nrow;
                    float4 b4 = *(const float4*)(nrow + 4);
                    v[0] = a.x  - ctr[ln][c1 + 0];
                    v[1] = a.y  - ctr[ln][c1 + 1];
                    v[2] = a.z  - ctr[ln][c1 + 2];
                    v[3] = a.w  - ctr[ln][c1 + 3];
                    v[4] = b4.x - ctr[ln][c1 + 4];
                    v[5] = b4.y - ctr[ln][c1 + 5];
                    v[6] = b4.z - ctr[ln][c1 + 6];
                    v[7] = b4.w - ctr[ln][c1 + 7];
                }
            } else {
                if (c0 == 0) {
                    const float* nrow = feat + ((size_t)b * N + nb[mrow]) * fs;
                    v[0] = ctr[ln][0]; v[1] = ctr[ln][1]; v[2] = ctr[ln][2];
                    v[3] = nrow[0] - ctr[ln][0];
                    v[4] = nrow[1] - ctr[ln][1];
                    v[5] = nrow[2] - ctr[ln][2];
                    v[6] = 0.f; v[7] = 0.f;
                } else {
#pragma unroll
                    for (int j = 0; j < 8; ++j) v[j] = 0.f;
                }
            }
            union { unsigned short u[8]; uint4 v4; } th, tl;
#pragma unroll
            for (int j = 0; j < 8; ++j) hilo(v[j], th.u[j], tl.u[j]);
            int off = mrow * CHB + ((ch * 16) ^ ((mrow & SWZ) << 4));
            *(uint4*)&Eh[off] = th.v4;
            *(uint4*)&El[off] = tl.v4;
        }
        __syncthreads();

        bf16x8 Bh[OTW][KSC], Bl[OTW][KSC];
#pragma unroll
        for (int ot = 0; ot < OTW; ++ot)
#pragma unroll
            for (int ksc = 0; ksc < KSC; ++ksc) {
                size_t fi = (size_t)((((wv * OTW + ot) * KS + kc * KSC + ksc) * 64 + lane)) << 3;
                Bh[ot][ksc] = *(const bf16x8*)(Wh + fi);
                Bl[ot][ksc] = *(const bf16x8*)(Wl + fi);
            }

#pragma unroll
        for (int mt = 0; mt < MT; ++mt) {
            int r0 = mt * 16 + (lane & 15);
            int cb = (lane >> 4) << 4;
            bf16x8 Ah[KSC], Al[KSC];
#pragma unroll
            for (int ksc = 0; ksc < KSC; ++ksc) {
                int off = r0 * CHB + (((ksc << 6) + cb) ^ ((r0 & SWZ) << 4));
                Ah[ksc] = *(const bf16x8*)&Eh[off];
                Al[ksc] = *(const bf16x8*)&El[off];
            }
#pragma unroll
            for (int ksc = 0; ksc < KSC; ++ksc)
#pragma unroll
                for (int ot = 0; ot < OTW; ++ot) {
                    acc[mt][ot] = __builtin_amdgcn_mfma_f32_16x16x32_bf16(Al[ksc], Bh[ot][ksc], acc[mt][ot], 0, 0, 0);
                    acc[mt][ot] = __builtin_amdgcn_mfma_f32_16x16x32_bf16(Ah[ksc], Bl[ot][ksc], acc[mt][ot], 0, 0, 0);
                    acc[mt][ot] = __builtin_amdgcn_mfma_f32_16x16x32_bf16(Ah[ksc], Bh[ot][ksc], acc[mt][ot], 0, 0, 0);
                }
        }
    }

#pragma unroll
    for (int ot = 0; ot < OTW; ++ot) {
        f32x4 v;
#pragma unroll
        for (int rr = 0; rr < 4; ++rr) {
            float m = acc[0][ot][rr];
#pragma unroll
            for (int mt = 1; mt < MT; ++mt) m = fmaxf(m, acc[mt][ot][rr]);
            if constexpr (TN == 4) m = fmaxf(m, __shfl_xor(m, 16));
            m = fmaxf(m, __shfl_xor(m, 32));
            v[rr] = m;
        }
        int o = (wv * OTW + ot) * 16 + (lane & 15);
        float s  = gp[o] * rsqrtf(vp[o] + EPS);
        float sh = bp[o] - mp[o] * s;
        bool valid = (TN == 8) ? (lane < 32) : (lane < 16);
        if (valid) {
            int lnb = (TN == 8) ? ((lane >> 4) << 2) : 0;
#pragma unroll
            for (int rr = 0; rr < 4; ++rr) {
                float h = fmaf(v[rr], s, sh);
                h = h > 0.f ? h : 0.2f * h;
                outBase[((size_t)b * N + n0 + lnb + rr) * 512 + o] = h;
            }
        }
    }
}

// ------------------------------------------------------------ global 512x512 MFMA (hi/lo), streaming K-loop
// block = 4 waves; wave = 32 rows x 64 cols (2 row-tiles x 4 otiles). No resident frag arrays -> no spill.
// grid = 8 b * 64 rowchunks * 2 colhalves = 1024
__global__ __launch_bounds__(256) void
global_mfma(const float* __restrict__ xcat,
            const unsigned short* __restrict__ Wh, const unsigned short* __restrict__ Wl,
            const float* __restrict__ gg, const float* __restrict__ bg,
            const float* __restrict__ mg, const float* __restrict__ vg,
            unsigned int* __restrict__ keys) {
    const int N = 2048, CV = 512;
    int b     = blockIdx.x & 7;
    int t     = blockIdx.x >> 3;
    int n0    = (t & 63) * 32;
    int colh  = t >> 6;
    int tid = threadIdx.x, lane = tid & 63, wv = tid >> 6;
    int obase = colh * 16 + wv * 4;     // otile base (4 otiles per wave)

    f32x4 acc0[4], acc1[4];
#pragma unroll
    for (int ot = 0; ot < 4; ++ot)
#pragma unroll
        for (int rr = 0; rr < 4; ++rr) { acc0[ot][rr] = 0.f; acc1[ot][rr] = 0.f; }

    const float* arow0 = xcat + ((size_t)b * N + n0 +      (lane & 15)) * CV + ((lane >> 4) << 3);
    const float* arow1 = xcat + ((size_t)b * N + n0 + 16 + (lane & 15)) * CV + ((lane >> 4) << 3);

    for (int ks = 0; ks < 16; ++ks) {
        // A fragments for the two row tiles (hi/lo from f32)
        bf16x8 Ah0, Al0, Ah1, Al1;
        {
            float4 a  = *(const float4*)(arow0 + ks * 32);
            float4 b4 = *(const float4*)(arow0 + ks * 32 + 4);
            union { unsigned short u[8]; bf16x8 v; } ch, cl;
            hilo(a.x,  ch.u[0], cl.u[0]); hilo(a.y,  ch.u[1], cl.u[1]);
            hilo(a.z,  ch.u[2], cl.u[2]); hilo(a.w,  ch.u[3], cl.u[3]);
            hilo(b4.x, ch.u[4], cl.u[4]); hilo(b4.y, ch.u[5], cl.u[5]);
            hilo(b4.z, ch.u[6], cl.u[6]); hilo(b4.w, ch.u[7], cl.u[7]);
            Ah0 = ch.v; Al0 = cl.v;
        }
        {
            float4 a  = *(const float4*)(arow1 + ks * 32);
            float4 b4 = *(const float4*)(arow1 + ks * 32 + 4);
            union { unsigned short u[8]; bf16x8 v; } ch, cl;
            hilo(a.x,  ch.u[0], cl.u[0]); hilo(a.y,  ch.u[1], cl.u[1]);
            hilo(a.z,  ch.u[2], cl.u[2]); hilo(a.w,  ch.u[3], cl.u[3]);
            hilo(b4.x, ch.u[4], cl.u[4]); hilo(b4.y, ch.u[5], cl.u[5]);
            hilo(b4.z, ch.u[6], cl.u[6]); hilo(b4.w, ch.u[7], cl.u[7]);
            Ah1 = ch.v; Al1 = cl.v;
        }
#pragma unroll
        for (int ot = 0; ot < 4; ++ot) {
            size_t fi = (size_t)((((obase + ot) * 16 + ks) * 64 + lane)) << 3;
            bf16x8 Bh = *(const bf16x8*)(Wh + fi);
            bf16x8 Bl = *(const bf16x8*)(Wl + fi);
            acc0[ot] = __builtin_amdgcn_mfma_f32_16x16x32_bf16(Al0, Bh, acc0[ot], 0, 0, 0);
            acc0[ot] = __builtin_amdgcn_mfma_f32_16x16x32_bf16(Ah0, Bl, acc0[ot], 0, 0, 0);
            acc0[ot] = __builtin_amdgcn_mfma_f32_16x16x32_bf16(Ah0, Bh, acc0[ot], 0, 0, 0);
            acc1[ot] = __builtin_amdgcn_mfma_f32_16x16x32_bf16(Al1, Bh, acc1[ot], 0, 0, 0);
            acc1[ot] = __builtin_amdgcn_mfma_f32_16x16x32_bf16(Ah1, Bl, acc1[ot], 0, 0, 0);
            acc1[ot] = __builtin_amdgcn_mfma_f32_16x16x32_bf16(Ah1, Bh, acc1[ot], 0, 0, 0);
        }
    }

#pragma unroll
    for (int ot = 0; ot < 4; ++ot) {
        f32x4 v;
#pragma unroll
        for (int rr = 0; rr < 4; ++rr) {
            float m = fmaxf(acc0[ot][rr], acc1[ot][rr]);
            m = fmaxf(m, __shfl_xor(m, 16));
            m = fmaxf(m, __shfl_xor(m, 32));
            v[rr] = m;
        }
        int o = (obase + ot) * 16 + (lane & 15);
        float s  = gg[o] * rsqrtf(vg[o] + EPS);
        float sh = bg[o] - mg[o] * s;
        if (lane < 16) {
            float hm = -INFINITY;
#pragma unroll
            for (int rr = 0; rr < 4; ++rr) {
                float h = fmaf(v[rr], s, sh);
                h = h > 0.f ? h : 0.2f * h;
                hm = fmaxf(hm, h);
            }
            atomicMax(&keys[b * 512 + o], fkey(hm));
        }
    }
}

__global__ void decode_kernel(const unsigned int* __restrict__ keys, float* __restrict__ out) {
    int id = blockIdx.x * 256 + threadIdx.x;
    if (id < 8 * 512) out[id] = funkey(keys[id]);
}

// ---------------------------------------------------------------- launcher
extern "C" void kernel_launch(void* const* d_in, const int* in_sizes, int n_in,
                              void* d_out, int out_size, void* d_ws, size_t ws_size,
                              hipStream_t stream) {
    const int B = 8, N = 2048, K = 20;
    const float* pts = (const float*)d_in[0];
    const float* w1 = (const float*)d_in[1];
    const float *g1 = (const float*)d_in[2], *b1 = (const float*)d_in[3],
                *m1 = (const float*)d_in[4], *v1 = (const float*)d_in[5];
    const float* w2 = (const float*)d_in[6];
    const float *g2 = (const float*)d_in[7], *b2 = (const float*)d_in[8],
                *m2 = (const float*)d_in[9], *v2 = (const float*)d_in[10];
    const float* w3 = (const float*)d_in[11];
    const float *g3 = (const float*)d_in[12], *b3 = (const float*)d_in[13],
                *m3 = (const float*)d_in[14], *v3 = (const float*)d_in[15];
    const float* w4 = (const float*)d_in[16];
    const float *g4 = (const float*)d_in[17], *b4 = (const float*)d_in[18],
                *m4 = (const float*)d_in[19], *v4 = (const float*)d_in[20];
    const float* wg = (const float*)d_in[21];
    const float *gg = (const float*)d_in[22], *bg = (const float*)d_in[23],
                *mg = (const float*)d_in[24], *vg = (const float*)d_in[25];

    // workspace layout
    float* ws   = (float*)d_ws;
    float* xcat = ws;                                    // 8*2048*512
    float* xT   = xcat + (size_t)B * N * 512;            // 8*128*2048
    float* xx   = xT + (size_t)B * 128 * N;              // 8*2048
    int*   idx  = (int*)(xx + B * N);                    // 8*2048*20
    unsigned short* wf1h = (unsigned short*)(idx + (size_t)B * N * K);
    unsigned short* wf1l = wf1h + 64 * 32;
    unsigned short* wf2h = wf1l + 64 * 32;
    unsigned short* wf2l = wf2h + 64 * 128;
    unsigned short* wf3h = wf2l + 64 * 128;
    unsigned short* wf3l = wf3h + 128 * 128;
    unsigned short* wf4h = wf3l + 128 * 128;
    unsigned short* wf4l = wf4h + 256 * 256;
    unsigned short* wfgh = wf4l + 256 * 256;
    unsigned short* wfgl = wfgh + 512 * 512;
    unsigned int* keys  = (unsigned int*)(wfgl + 512 * 512);

    // pack weight fragments (bf16 hi/lo)
    wfrag_kernel<<<(64 * 32 + 255) / 256, 256, 0, stream>>>(w1, 64, 6, 32, wf1h, wf1l);
    wfrag_kernel<<<(64 * 128 + 255) / 256, 256, 0, stream>>>(w2, 64, 128, 128, wf2h, wf2l);
    wfrag_kernel<<<(128 * 128 + 255) / 256, 256, 0, stream>>>(w3, 128, 128, 128, wf3h, wf3l);
    wfrag_kernel<<<(256 * 256 + 255) / 256, 256, 0, stream>>>(w4, 256, 256, 256, wf4h, wf4l);
    wfrag_kernel<<<(512 * 512 + 255) / 256, 256, 0, stream>>>(wg, 512, 512, 512, wfgh, wfgl);

    // ---- layer 1: C=3 -> 64, out offset 0
    transpose_feat_kernel<<<(B * 3 * N + 255) / 256, 256, 0, stream>>>(pts, 3, 3, xT);
    sumsq_kernel<<<(B * N + 255) / 256, 256, 0, stream>>>(xT, 3, xx);
    dist_topk_kernel<<<B * (N / 8), 512, 0, stream>>>(xT, xx, 3, idx);
    edgeconv_mfma<3, 64, 8, 4, 1><<<B * (N / 8), 256, 0, stream>>>(pts, 3, idx, wf1h, wf1l, g1, b1, m1, v1, xcat + 0);

    // ---- layer 2: 64 -> 64, out offset 64
    transpose_feat_kernel<<<(B * 64 * N + 255) / 256, 256, 0, stream>>>(xcat + 0, 512, 64, xT);
    sumsq_kernel<<<(B * N + 255) / 256, 256, 0, stream>>>(xT, 64, xx);
    dist_topk_kernel<<<B * (N / 8), 512, 0, stream>>>(xT, xx, 64, idx);
    edgeconv_mfma<64, 64, 4, 4, 1><<<B * (N / 4), 256, 0, stream>>>(xcat + 0, 512, idx, wf2h, wf2l, g2, b2, m2, v2, xcat + 64);

    // ---- layer 3: 64 -> 128, out offset 128
    transpose_feat_kernel<<<(B * 64 * N + 255) / 256, 256, 0, stream>>>(xcat + 64, 512, 64, xT);
    sumsq_kernel<<<(B * N + 255) / 256, 256, 0, stream>>>(xT, 64, xx);
    dist_topk_kernel<<<B * (N / 8), 512, 0, stream>>>(xT, xx, 64, idx);
    edgeconv_mfma<64, 128, 4, 8, 1><<<B * (N / 4), 512, 0, stream>>>(xcat + 64, 512, idx, wf3h, wf3l, g3, b3, m3, v3, xcat + 128);

    // ---- layer 4: 128 -> 256, out offset 256 (K-chunked: NKC=2)
    transpose_feat_kernel<<<(B * 128 * N + 255) / 256, 256, 0, stream>>>(xcat + 128, 512, 128, xT);
    sumsq_kernel<<<(B * N + 255) / 256, 256, 0, stream>>>(xT, 128, xx);
    dist_topk_kernel<<<B * (N / 8), 512, 0, stream>>>(xT, xx, 128, idx);
    edgeconv_mfma<128, 256, 4, 8, 2><<<B * (N / 4), 512, 0, stream>>>(xcat + 128, 512, idx, wf4h, wf4l, g4, b4, m4, v4, xcat + 256);

    // ---- global layer + max over N
    hipMemsetAsync(keys, 0, (size_t)B * 512 * sizeof(unsigned int), stream);
    global_mfma<<<B * 128, 256, 0, stream>>>(xcat, wfgh, wfgl, gg, bg, mg, vg, keys);
    decode_kernel<<<(B * 512 + 255) / 256, 256, 0, stream>>>(keys, (float*)d_out);
}

// Round 8
// 924.928 us; speedup vs baseline: 3.6710x; 1.0375x over previous
//
#include <hip/hip_runtime.h>
#include <hip/hip_bf16.h>

#define EPS 1e-5f

typedef __attribute__((ext_vector_type(8))) short bf16x8;
typedef __attribute__((ext_vector_type(4))) float f32x4;

// ---------------------------------------------------------------- utilities
__device__ __forceinline__ unsigned int fkey(float f) {
    unsigned int b = __float_as_uint(f);
    return (b & 0x80000000u) ? ~b : (b | 0x80000000u);
}
__device__ __forceinline__ float funkey(unsigned int k) {
    unsigned int b = (k & 0x80000000u) ? (k & 0x7fffffffu) : ~k;
    return __uint_as_float(b);
}
__device__ __forceinline__ unsigned short f2bu(float f) {
    union { __hip_bfloat16 h; unsigned short u; } cv;
    cv.h = __float2bfloat16(f);
    return cv.u;
}
__device__ __forceinline__ float bu2f(unsigned short u) {
    return __uint_as_float(((unsigned int)u) << 16);
}
__device__ __forceinline__ void hilo(float v, unsigned short& h, unsigned short& l) {
    h = f2bu(v);
    l = f2bu(v - bu2f(h));
}

// ------------------------------------------------------------ weight fragment packing (hi+lo planes)
__global__ void wfrag_kernel(const float* __restrict__ W, int CO, int C2, int C2P,
                             unsigned short* __restrict__ Fh, unsigned short* __restrict__ Fl) {
    int id = blockIdx.x * 256 + threadIdx.x;
    int total = CO * C2P;
    if (id >= total) return;
    int j = id & 7, lane = (id >> 3) & 63, t = id >> 9;
    int KS = C2P >> 5;
    int ks = t % KS, ot = t / KS;
    int o = ot * 16 + (lane & 15);
    int c = ks * 32 + ((lane >> 4) << 3) + j;
    float v = (c < C2) ? W[o * C2 + c] : 0.f;
    unsigned short h, l;
    hilo(v, h, l);
    Fh[id] = h;
    Fl[id] = l;
}

// ------------------------------------------------------------ transpose feat: xT[b][c][m]
__global__ void transpose_feat_kernel(const float* __restrict__ feat, int fstride, int C,
                                      float* __restrict__ xT) {
    const int N = 2048;
    int id = blockIdx.x * 256 + threadIdx.x;
    if (id >= 8 * C * N) return;
    int m = id & 2047;
    int bc = id >> 11;
    int c = bc % C, b = bc / C;
    xT[id] = feat[((size_t)b * N + m) * fstride + c];
}

// ------------------------------------------------------------ xx[b][n] = sum_c x^2
__global__ void sumsq_kernel(const float* __restrict__ xT, int C, float* __restrict__ xx) {
    const int N = 2048;
    int id = blockIdx.x * 256 + threadIdx.x;
    if (id >= 8 * N) return;
    int b = id >> 11, n = id & 2047;
    const float* p = xT + (size_t)b * C * N + n;
    float s = 0.f;
    for (int c = 0; c < C; ++c) { float v = p[(size_t)c * N]; s = fmaf(v, v, s); }
    xx[id] = s;
}

// ------------------------------------------------------------ distance tile + wave-local top-20
// 512 threads, TM=8 rows/block; b = blockIdx&7 pins each batch to one XCD.
// __launch_bounds__(512,4): min 4 waves/EU -> VGPR cap 128, keeps 32 u32 keys RESIDENT (no scratch spill).
// phase B: u32 keys; per round: max-reduce, local-first-match-slot (compile-time slot consts), purge-by-slot.
__global__ __launch_bounds__(512, 4) void
dist_topk_kernel(const float* __restrict__ xT, const float* __restrict__ xx,
                 int C, int* __restrict__ idxOut) {
    const int N = 2048, TM = 8;
    int b  = blockIdx.x & 7;
    int n0 = (blockIdx.x >> 3) * TM;
    int tid = threadIdx.x;
    __shared__ float dist[TM][N];          // 64 KB

    const float* xTb = xT + (size_t)b * C * N;

    // ---------------- phase A: dot products, 8 rows x 4 cols per thread
    float acc[TM][4];
#pragma unroll
    for (int r = 0; r < TM; ++r)
#pragma unroll
        for (int i = 0; i < 4; ++i) acc[r][i] = 0.f;

#pragma unroll 2
    for (int c = 0; c < C; ++c) {
        const float* row = xTb + (size_t)c * N;
        float4 cv = *(const float4*)(row + 4 * tid);
        float q[TM];
#pragma unroll
        for (int r = 0; r < TM; ++r) q[r] = row[n0 + r];
#pragma unroll
        for (int r = 0; r < TM; ++r) {
            acc[r][0] = fmaf(q[r], cv.x, acc[r][0]);
            acc[r][1] = fmaf(q[r], cv.y, acc[r][1]);
            acc[r][2] = fmaf(q[r], cv.z, acc[r][2]);
            acc[r][3] = fmaf(q[r], cv.w, acc[r][3]);
        }
    }
    {
        const float* xxb = xx + (size_t)b * N;
        float4 xv = *(const float4*)(xxb + 4 * tid);
        float xq[TM];
#pragma unroll
        for (int r = 0; r < TM; ++r) xq[r] = xxb[n0 + r];
#pragma unroll
        for (int r = 0; r < TM; ++r) {
            float4 d;
            d.x = 2.f * acc[r][0] - xq[r] - xv.x;
            d.y = 2.f * acc[r][1] - xq[r] - xv.y;
            d.z = 2.f * acc[r][2] - xq[r] - xv.z;
            d.w = 2.f * acc[r][3] - xq[r] - xv.w;
            *(float4*)&dist[r][4 * tid] = d;
        }
    }
    __syncthreads();

    // ---------------- phase B: one row per wave, u32 monotone keys, exact stable ties
    // element (j,i) of lane: m = j*256 + 4*lane + i ; slot = j*4+i (compile-time)
    int lane = tid & 63;
    int r = tid >> 6;
    unsigned int key[8][4];
#pragma unroll
    for (int j = 0; j < 8; ++j) {
        float4 v = *(const float4*)&dist[r][j * 256 + 4 * lane];
        key[j][0] = fkey(v.x);
        key[j][1] = fkey(v.y);
        key[j][2] = fkey(v.z);
        key[j][3] = fkey(v.w);
    }
    const unsigned int BIG = 0xFFFFu;
    int resm = 0;
    for (int k = 0; k < 20; ++k) {
        // ---- pass 1: global max value
        unsigned int gm;
        {
            unsigned int t0 = key[0][0] > key[0][1] ? key[0][0] : key[0][1];
            unsigned int t1 = key[0][2] > key[0][3] ? key[0][2] : key[0][3];
            gm = t0 > t1 ? t0 : t1;
#pragma unroll
            for (int j = 1; j < 8; ++j) {
                unsigned int a0 = key[j][0] > key[j][1] ? key[j][0] : key[j][1];
                unsigned int a1 = key[j][2] > key[j][3] ? key[j][2] : key[j][3];
                unsigned int a  = a0 > a1 ? a0 : a1;
                gm = gm > a ? gm : a;
            }
        }
#pragma unroll
        for (int s = 1; s < 64; s <<= 1) {
            unsigned int o = (unsigned int)__shfl_xor((int)gm, s);
            gm = gm > o ? gm : o;
        }
        // ---- pass 2: local first-match slot (ascending m within lane), then global min m
        unsigned int ls = BIG;
#pragma unroll
        for (int j = 0; j < 8; ++j)
#pragma unroll
            for (int i = 0; i < 4; ++i) {
                unsigned int cand = (key[j][i] == gm) ? (unsigned int)(j * 4 + i) : BIG;
                ls = ls < cand ? ls : cand;
            }
        unsigned int lmm = ((ls & ~3u) << 6) | ((unsigned int)lane << 2) | (ls & 3u);
        lmm = (ls == BIG) ? BIG : lmm;
#pragma unroll
        for (int s = 1; s < 64; s <<= 1) {
            unsigned int o = (unsigned int)__shfl_xor((int)lmm, s);
            lmm = lmm < o ? lmm : o;
        }
        // ---- pass 3: purge exactly element m == lmm (slot-based, 2 ops/elem)
        unsigned int glane = (lmm >> 2) & 63u;
        unsigned int gslot = ((lmm >> 8) << 2) | (lmm & 3u);
        unsigned int pa = ((unsigned int)lane == glane) ? gslot : BIG;
#pragma unroll
        for (int j = 0; j < 8; ++j)
#pragma unroll
            for (int i = 0; i < 4; ++i)
                key[j][i] = (pa == (unsigned int)(j * 4 + i)) ? 0u : key[j][i];
        if (lane == k) resm = (int)lmm;
    }
    if (lane < 20) idxOut[((size_t)b * N + n0 + r) * 20 + lane] = resm;
}

// ------------------------------------------------------------ MFMA edgeconv, hi/lo split (3 MFMA per product)
template <int CI, int CO, int TN, int WAVES, int NKC>
__global__ __launch_bounds__(WAVES * 64) void
edgeconv_mfma(const float* __restrict__ feat, int fs, const int* __restrict__ idx,
              const unsigned short* __restrict__ Wh, const unsigned short* __restrict__ Wl,
              const float* __restrict__ gp, const float* __restrict__ bp,
              const float* __restrict__ mp, const float* __restrict__ vp,
              float* __restrict__ outBase) {
    constexpr int N = 2048, K = 20;
    constexpr int C2 = 2 * CI;
    constexpr int C2P = (C2 < 32) ? 32 : C2;
    constexpr int KS = C2P / 32;
    constexpr int KSC = KS / NKC;
    constexpr int CCOLS = KSC * 32;
    constexpr int CHB = CCOLS * 2;
    constexpr int OT = CO / 16;
    constexpr int OTW = OT / WAVES;
    constexpr int M = TN * K;
    constexpr int MT = M / 16;
    constexpr int CH = CCOLS / 8;
    constexpr int SWZ = (CHB >= 128) ? 7 : (CHB / 16 - 1);
    constexpr int THREADS = WAVES * 64;

    int b  = blockIdx.x & 7;
    int n0 = (blockIdx.x >> 3) * TN;
    int tid = threadIdx.x;
    int lane = tid & 63, wv = tid >> 6;

    __shared__ float ctr[TN][CI];
    __shared__ int nb[M];
    __shared__ __align__(16) unsigned char Eh[M * CHB];
    __shared__ __align__(16) unsigned char El[M * CHB];

    for (int e = tid; e < TN * CI; e += THREADS) {
        int ln = e / CI, c = e % CI;
        ctr[ln][c] = feat[((size_t)b * N + n0 + ln) * fs + c];
    }
    for (int e = tid; e < M; e += THREADS) {
        int k = e / TN, ln = e % TN;
        nb[e] = idx[((size_t)b * N + n0 + ln) * K + k];
    }
    __syncthreads();

    f32x4 acc[MT][OTW];
#pragma unroll
    for (int mt = 0; mt < MT; ++mt)
#pragma unroll
        for (int ot = 0; ot < OTW; ++ot)
#pragma unroll
            for (int rr = 0; rr < 4; ++rr) acc[mt][ot][rr] = 0.f;

    for (int kc = 0; kc < NKC; ++kc) {
        if (kc) __syncthreads();
        for (int e = tid; e < M * CH; e += THREADS) {
            int mrow = e / CH, ch = e - mrow * CH;
            int c0 = kc * CCOLS + ch * 8;
            int ln = mrow % TN;
            float v[8];
            if constexpr (CI >= 8) {
                if (c0 < CI) {
#pragma unroll
                    for (int j = 0; j < 8; ++j) v[j] = ctr[ln][c0 + j];
                } else {
                    int c1 = c0 - CI;
                    const float* nrow = feat + ((size_t)b * N + nb[mrow]) * fs + c1;
                    float4 a  = *(const float4*)nrow;
                    float4 b4 = *(const float4*)(nrow + 4);
                    v[0] = a.x  - ctr[ln][c1 + 0];
                    v[1] = a.y  - ctr[ln][c1 + 1];
                    v[2] = a.z  - ctr[ln][c1 + 2];
                    v[3] = a.w  - ctr[ln][c1 + 3];
                    v[4] = b4.x - ctr[ln][c1 + 4];
                    v[5] = b4.y - ctr[ln][c1 + 5];
                    v[6] = b4.z - ctr[ln][c1 + 6];
                    v[7] = b4.w - ctr[ln][c1 + 7];
                }
            } else {
                if (c0 == 0) {
                    const float* nrow = feat + ((size_t)b * N + nb[mrow]) * fs;
                    v[0] = ctr[ln][0]; v[1] = ctr[ln][1]; v[2] = ctr[ln][2];
                    v[3] = nrow[0] - ctr[ln][0];
                    v[4] = nrow[1] - ctr[ln][1];
                    v[5] = nrow[2] - ctr[ln][2];
                    v[6] = 0.f; v[7] = 0.f;
                } else {
#pragma unroll
                    for (int j = 0; j < 8; ++j) v[j] = 0.f;
                }
            }
            union { unsigned short u[8]; uint4 v4; } th, tl;
#pragma unroll
            for (int j = 0; j < 8; ++j) hilo(v[j], th.u[j], tl.u[j]);
            int off = mrow * CHB + ((ch * 16) ^ ((mrow & SWZ) << 4));
            *(uint4*)&Eh[off] = th.v4;
            *(uint4*)&El[off] = tl.v4;
        }
        __syncthreads();

        bf16x8 Bh[OTW][KSC], Bl[OTW][KSC];
#pragma unroll
        for (int ot = 0; ot < OTW; ++ot)
#pragma unroll
            for (int ksc = 0; ksc < KSC; ++ksc) {
                size_t fi = (size_t)((((wv * OTW + ot) * KS + kc * KSC + ksc) * 64 + lane)) << 3;
                Bh[ot][ksc] = *(const bf16x8*)(Wh + fi);
                Bl[ot][ksc] = *(const bf16x8*)(Wl + fi);
            }

#pragma unroll
        for (int mt = 0; mt < MT; ++mt) {
            int r0 = mt * 16 + (lane & 15);
            int cb = (lane >> 4) << 4;
            bf16x8 Ah[KSC], Al[KSC];
#pragma unroll
            for (int ksc = 0; ksc < KSC; ++ksc) {
                int off = r0 * CHB + (((ksc << 6) + cb) ^ ((r0 & SWZ) << 4));
                Ah[ksc] = *(const bf16x8*)&Eh[off];
                Al[ksc] = *(const bf16x8*)&El[off];
            }
#pragma unroll
            for (int ksc = 0; ksc < KSC; ++ksc)
#pragma unroll
                for (int ot = 0; ot < OTW; ++ot) {
                    acc[mt][ot] = __builtin_amdgcn_mfma_f32_16x16x32_bf16(Al[ksc], Bh[ot][ksc], acc[mt][ot], 0, 0, 0);
                    acc[mt][ot] = __builtin_amdgcn_mfma_f32_16x16x32_bf16(Ah[ksc], Bl[ot][ksc], acc[mt][ot], 0, 0, 0);
                    acc[mt][ot] = __builtin_amdgcn_mfma_f32_16x16x32_bf16(Ah[ksc], Bh[ot][ksc], acc[mt][ot], 0, 0, 0);
                }
        }
    }

#pragma unroll
    for (int ot = 0; ot < OTW; ++ot) {
        f32x4 v;
#pragma unroll
        for (int rr = 0; rr < 4; ++rr) {
            float m = acc[0][ot][rr];
#pragma unroll
            for (int mt = 1; mt < MT; ++mt) m = fmaxf(m, acc[mt][ot][rr]);
            if constexpr (TN == 4) m = fmaxf(m, __shfl_xor(m, 16));
            m = fmaxf(m, __shfl_xor(m, 32));
            v[rr] = m;
        }
        int o = (wv * OTW + ot) * 16 + (lane & 15);
        float s  = gp[o] * rsqrtf(vp[o] + EPS);
        float sh = bp[o] - mp[o] * s;
        bool valid = (TN == 8) ? (lane < 32) : (lane < 16);
        if (valid) {
            int lnb = (TN == 8) ? ((lane >> 4) << 2) : 0;
#pragma unroll
            for (int rr = 0; rr < 4; ++rr) {
                float h = fmaf(v[rr], s, sh);
                h = h > 0.f ? h : 0.2f * h;
                outBase[((size_t)b * N + n0 + lnb + rr) * 512 + o] = h;
            }
        }
    }
}

// ------------------------------------------------------------ global 512x512 MFMA (hi/lo), streaming K-loop
__global__ __launch_bounds__(256) void
global_mfma(const float* __restrict__ xcat,
            const unsigned short* __restrict__ Wh, const unsigned short* __restrict__ Wl,
            const float* __restrict__ gg, const float* __restrict__ bg,
            const float* __restrict__ mg, const float* __restrict__ vg,
            unsigned int* __restrict__ keys) {
    const int N = 2048, CV = 512;
    int b     = blockIdx.x & 7;
    int t     = blockIdx.x >> 3;
    int n0    = (t & 63) * 32;
    int colh  = t >> 6;
    int tid = threadIdx.x, lane = tid & 63, wv = tid >> 6;
    int obase = colh * 16 + wv * 4;

    f32x4 acc0[4], acc1[4];
#pragma unroll
    for (int ot = 0; ot < 4; ++ot)
#pragma unroll
        for (int rr = 0; rr < 4; ++rr) { acc0[ot][rr] = 0.f; acc1[ot][rr] = 0.f; }

    const float* arow0 = xcat + ((size_t)b * N + n0 +      (lane & 15)) * CV + ((lane >> 4) << 3);
    const float* arow1 = xcat + ((size_t)b * N + n0 + 16 + (lane & 15)) * CV + ((lane >> 4) << 3);

    for (int ks = 0; ks < 16; ++ks) {
        bf16x8 Ah0, Al0, Ah1, Al1;
        {
            float4 a  = *(const float4*)(arow0 + ks * 32);
            float4 b4 = *(const float4*)(arow0 + ks * 32 + 4);
            union { unsigned short u[8]; bf16x8 v; } ch, cl;
            hilo(a.x,  ch.u[0], cl.u[0]); hilo(a.y,  ch.u[1], cl.u[1]);
            hilo(a.z,  ch.u[2], cl.u[2]); hilo(a.w,  ch.u[3], cl.u[3]);
            hilo(b4.x, ch.u[4], cl.u[4]); hilo(b4.y, ch.u[5], cl.u[5]);
            hilo(b4.z, ch.u[6], cl.u[6]); hilo(b4.w, ch.u[7], cl.u[7]);
            Ah0 = ch.v; Al0 = cl.v;
        }
        {
            float4 a  = *(const float4*)(arow1 + ks * 32);
            float4 b4 = *(const float4*)(arow1 + ks * 32 + 4);
            union { unsigned short u[8]; bf16x8 v; } ch, cl;
            hilo(a.x,  ch.u[0], cl.u[0]); hilo(a.y,  ch.u[1], cl.u[1]);
            hilo(a.z,  ch.u[2], cl.u[2]); hilo(a.w,  ch.u[3], cl.u[3]);
            hilo(b4.x, ch.u[4], cl.u[4]); hilo(b4.y, ch.u[5], cl.u[5]);
            hilo(b4.z, ch.u[6], cl.u[6]); hilo(b4.w, ch.u[7], cl.u[7]);
            Ah1 = ch.v; Al1 = cl.v;
        }
#pragma unroll
        for (int ot = 0; ot < 4; ++ot) {
            size_t fi = (size_t)((((obase + ot) * 16 + ks) * 64 + lane)) << 3;
            bf16x8 Bh = *(const bf16x8*)(Wh + fi);
            bf16x8 Bl = *(const bf16x8*)(Wl + fi);
            acc0[ot] = __builtin_amdgcn_mfma_f32_16x16x32_bf16(Al0, Bh, acc0[ot], 0, 0, 0);
            acc0[ot] = __builtin_amdgcn_mfma_f32_16x16x32_bf16(Ah0, Bl, acc0[ot], 0, 0, 0);
            acc0[ot] = __builtin_amdgcn_mfma_f32_16x16x32_bf16(Ah0, Bh, acc0[ot], 0, 0, 0);
            acc1[ot] = __builtin_amdgcn_mfma_f32_16x16x32_bf16(Al1, Bh, acc1[ot], 0, 0, 0);
            acc1[ot] = __builtin_amdgcn_mfma_f32_16x16x32_bf16(Ah1, Bl, acc1[ot], 0, 0, 0);
            acc1[ot] = __builtin_amdgcn_mfma_f32_16x16x32_bf16(Ah1, Bh, acc1[ot], 0, 0, 0);
        }
    }

#pragma unroll
    for (int ot = 0; ot < 4; ++ot) {
        f32x4 v;
#pragma unroll
        for (int rr = 0; rr < 4; ++rr) {
            float m = fmaxf(acc0[ot][rr], acc1[ot][rr]);
            m = fmaxf(m, __shfl_xor(m, 16));
            m = fmaxf(m, __shfl_xor(m, 32));
            v[rr] = m;
        }
        int o = (obase + ot) * 16 + (lane & 15);
        float s  = gg[o] * rsqrtf(vg[o] + EPS);
        float sh = bg[o] - mg[o] * s;
        if (lane < 16) {
            float hm = -INFINITY;
#pragma unroll
            for (int rr = 0; rr < 4; ++rr) {
                float h = fmaf(v[rr], s, sh);
                h = h > 0.f ? h : 0.2f * h;
                hm = fmaxf(hm, h);
            }
            atomicMax(&keys[b * 512 + o], fkey(hm));
        }
    }
}

__global__ void decode_kernel(const unsigned int* __restrict__ keys, float* __restrict__ out) {
    int id = blockIdx.x * 256 + threadIdx.x;
    if (id < 8 * 512) out[id] = funkey(keys[id]);
}

// ---------------------------------------------------------------- launcher
extern "C" void kernel_launch(void* const* d_in, const int* in_sizes, int n_in,
                              void* d_out, int out_size, void* d_ws, size_t ws_size,
                              hipStream_t stream) {
    const int B = 8, N = 2048, K = 20;
    const float* pts = (const float*)d_in[0];
    const float* w1 = (const float*)d_in[1];
    const float *g1 = (const float*)d_in[2], *b1 = (const float*)d_in[3],
                *m1 = (const float*)d_in[4], *v1 = (const float*)d_in[5];
    const float* w2 = (const float*)d_in[6];
    const float *g2 = (const float*)d_in[7], *b2 = (const float*)d_in[8],
                *m2 = (const float*)d_in[9], *v2 = (const float*)d_in[10];
    const float* w3 = (const float*)d_in[11];
    const float *g3 = (const float*)d_in[12], *b3 = (const float*)d_in[13],
                *m3 = (const float*)d_in[14], *v3 = (const float*)d_in[15];
    const float* w4 = (const float*)d_in[16];
    const float *g4 = (const float*)d_in[17], *b4 = (const float*)d_in[18],
                *m4 = (const float*)d_in[19], *v4 = (const float*)d_in[20];
    const float* wg = (const float*)d_in[21];
    const float *gg = (const float*)d_in[22], *bg = (const float*)d_in[23],
                *mg = (const float*)d_in[24], *vg = (const float*)d_in[25];

    // workspace layout
    float* ws   = (float*)d_ws;
    float* xcat = ws;                                    // 8*2048*512
    float* xT   = xcat + (size_t)B * N * 512;            // 8*128*2048
    float* xx   = xT + (size_t)B * 128 * N;              // 8*2048
    int*   idx  = (int*)(xx + B * N);                    // 8*2048*20
    unsigned short* wf1h = (unsigned short*)(idx + (size_t)B * N * K);
    unsigned short* wf1l = wf1h + 64 * 32;
    unsigned short* wf2h = wf1l + 64 * 32;
    unsigned short* wf2l = wf2h + 64 * 128;
    unsigned short* wf3h = wf2l + 64 * 128;
    unsigned short* wf3l = wf3h + 128 * 128;
    unsigned short* wf4h = wf3l + 128 * 128;
    unsigned short* wf4l = wf4h + 256 * 256;
    unsigned short* wfgh = wf4l + 256 * 256;
    unsigned short* wfgl = wfgh + 512 * 512;
    unsigned int* keys  = (unsigned int*)(wfgl + 512 * 512);

    // pack weight fragments (bf16 hi/lo)
    wfrag_kernel<<<(64 * 32 + 255) / 256, 256, 0, stream>>>(w1, 64, 6, 32, wf1h, wf1l);
    wfrag_kernel<<<(64 * 128 + 255) / 256, 256, 0, stream>>>(w2, 64, 128, 128, wf2h, wf2l);
    wfrag_kernel<<<(128 * 128 + 255) / 256, 256, 0, stream>>>(w3, 128, 128, 128, wf3h, wf3l);
    wfrag_kernel<<<(256 * 256 + 255) / 256, 256, 0, stream>>>(w4, 256, 256, 256, wf4h, wf4l);
    wfrag_kernel<<<(512 * 512 + 255) / 256, 256, 0, stream>>>(wg, 512, 512, 512, wfgh, wfgl);

    // ---- layer 1: C=3 -> 64, out offset 0
    transpose_feat_kernel<<<(B * 3 * N + 255) / 256, 256, 0, stream>>>(pts, 3, 3, xT);
    sumsq_kernel<<<(B * N + 255) / 256, 256, 0, stream>>>(xT, 3, xx);
    dist_topk_kernel<<<B * (N / 8), 512, 0, stream>>>(xT, xx, 3, idx);
    edgeconv_mfma<3, 64, 8, 4, 1><<<B * (N / 8), 256, 0, stream>>>(pts, 3, idx, wf1h, wf1l, g1, b1, m1, v1, xcat + 0);

    // ---- layer 2: 64 -> 64, out offset 64
    transpose_feat_kernel<<<(B * 64 * N + 255) / 256, 256, 0, stream>>>(xcat + 0, 512, 64, xT);
    sumsq_kernel<<<(B * N + 255) / 256, 256, 0, stream>>>(xT, 64, xx);
    dist_topk_kernel<<<B * (N / 8), 512, 0, stream>>>(xT, xx, 64, idx);
    edgeconv_mfma<64, 64, 4, 4, 1><<<B * (N / 4), 256, 0, stream>>>(xcat + 0, 512, idx, wf2h, wf2l, g2, b2, m2, v2, xcat + 64);

    // ---- layer 3: 64 -> 128, out offset 128
    transpose_feat_kernel<<<(B * 64 * N + 255) / 256, 256, 0, stream>>>(xcat + 64, 512, 64, xT);
    sumsq_kernel<<<(B * N + 255) / 256, 256, 0, stream>>>(xT, 64, xx);
    dist_topk_kernel<<<B * (N / 8), 512, 0, stream>>>(xT, xx, 64, idx);
    edgeconv_mfma<64, 128, 4, 8, 1><<<B * (N / 4), 512, 0, stream>>>(xcat + 64, 512, idx, wf3h, wf3l, g3, b3, m3, v3, xcat + 128);

    // ---- layer 4: 128 -> 256, out offset 256 (K-chunked: NKC=2)
    transpose_feat_kernel<<<(B * 128 * N + 255) / 256, 256, 0, stream>>>(xcat + 128, 512, 128, xT);
    sumsq_kernel<<<(B * N + 255) / 256, 256, 0, stream>>>(xT, 128, xx);
    dist_topk_kernel<<<B * (N / 8), 512, 0, stream>>>(xT, xx, 128, idx);
    edgeconv_mfma<128, 256, 4, 8, 2><<<B * (N / 4), 512, 0, stream>>>(xcat + 128, 512, idx, wf4h, wf4l, g4, b4, m4, v4, xcat + 256);

    // ---- global layer + max over N
    hipMemsetAsync(keys, 0, (size_t)B * 512 * sizeof(unsigned int), stream);
    global_mfma<<<B * 128, 256, 0, stream>>>(xcat, wfgh, wfgl, gg, bg, mg, vg, keys);
    decode_kernel<<<(B * 512 + 255) / 256, 256, 0, stream>>>(keys, (float*)d_out);
}

// Round 9
// 923.713 us; speedup vs baseline: 3.6759x; 1.0013x over previous
//
#include <hip/hip_runtime.h>
#include <hip/hip_bf16.h>

#define EPS 1e-5f

typedef __attribute__((ext_vector_type(8))) short bf16x8;
typedef __attribute__((ext_vector_type(4))) float f32x4;

// ---------------------------------------------------------------- utilities
__device__ __forceinline__ unsigned int fkey(float f) {
    unsigned int b = __float_as_uint(f);
    return (b & 0x80000000u) ? ~b : (b | 0x80000000u);
}
__device__ __forceinline__ float funkey(unsigned int k) {
    unsigned int b = (k & 0x80000000u) ? (k & 0x7fffffffu) : ~k;
    return __uint_as_float(b);
}
__device__ __forceinline__ unsigned short f2bu(float f) {
    union { __hip_bfloat16 h; unsigned short u; } cv;
    cv.h = __float2bfloat16(f);
    return cv.u;
}
__device__ __forceinline__ float bu2f(unsigned short u) {
    return __uint_as_float(((unsigned int)u) << 16);
}
__device__ __forceinline__ void hilo(float v, unsigned short& h, unsigned short& l) {
    h = f2bu(v);
    l = f2bu(v - bu2f(h));
}

// ------------------------------------------------------------ weight fragment packing (hi+lo planes)
__global__ void wfrag_kernel(const float* __restrict__ W, int CO, int C2, int C2P,
                             unsigned short* __restrict__ Fh, unsigned short* __restrict__ Fl) {
    int id = blockIdx.x * 256 + threadIdx.x;
    int total = CO * C2P;
    if (id >= total) return;
    int j = id & 7, lane = (id >> 3) & 63, t = id >> 9;
    int KS = C2P >> 5;
    int ks = t % KS, ot = t / KS;
    int o = ot * 16 + (lane & 15);
    int c = ks * 32 + ((lane >> 4) << 3) + j;
    float v = (c < C2) ? W[o * C2 + c] : 0.f;
    unsigned short h, l;
    hilo(v, h, l);
    Fh[id] = h;
    Fl[id] = l;
}

// ------------------------------------------------------------ transpose feat: xT[b][c][m]
__global__ void transpose_feat_kernel(const float* __restrict__ feat, int fstride, int C,
                                      float* __restrict__ xT) {
    const int N = 2048;
    int id = blockIdx.x * 256 + threadIdx.x;
    if (id >= 8 * C * N) return;
    int m = id & 2047;
    int bc = id >> 11;
    int c = bc % C, b = bc / C;
    xT[id] = feat[((size_t)b * N + m) * fstride + c];
}

// ------------------------------------------------------------ xx[b][n] = sum_c x^2
__global__ void sumsq_kernel(const float* __restrict__ xT, int C, float* __restrict__ xx) {
    const int N = 2048;
    int id = blockIdx.x * 256 + threadIdx.x;
    if (id >= 8 * N) return;
    int b = id >> 11, n = id & 2047;
    const float* p = xT + (size_t)b * C * N + n;
    float s = 0.f;
    for (int c = 0; c < C; ++c) { float v = p[(size_t)c * N]; s = fmaf(v, v, s); }
    xx[id] = s;
}

// ------------------------------------------------------------ distance tile + wave-local top-20
// 512 threads, TM=8 rows/block; b = blockIdx&7 pins each batch to one XCD.
// Phase A: q vectors loaded CONTIGUOUSLY from row-major feat (uniform float4, c-unroll 4);
//          column data from xT (per-lane float4).
// Phase B: per round ONE packed u64 reduce: P = key<<16 | (0xFFFF - m) -> max P = max key, min m.
__global__ __launch_bounds__(512, 4) void
dist_topk_kernel(const float* __restrict__ xT,
                 const float* __restrict__ feat, int fs,
                 const float* __restrict__ xx,
                 int C, int* __restrict__ idxOut) {
    const int N = 2048, TM = 8;
    int b  = blockIdx.x & 7;
    int n0 = (blockIdx.x >> 3) * TM;
    int tid = threadIdx.x;
    __shared__ float dist[TM][N];          // 64 KB

    const float* xTb = xT + (size_t)b * C * N;

    // ---------------- phase A: dot products, 8 rows x 4 cols per thread
    float acc[TM][4];
#pragma unroll
    for (int r = 0; r < TM; ++r)
#pragma unroll
        for (int i = 0; i < 4; ++i) acc[r][i] = 0.f;

    int c0 = 0;
    for (; c0 + 4 <= C; c0 += 4) {
        float4 qf[TM];
#pragma unroll
        for (int r = 0; r < TM; ++r)
            qf[r] = *(const float4*)(feat + ((size_t)b * N + n0 + r) * fs + c0);
#pragma unroll
        for (int cc = 0; cc < 4; ++cc) {
            const float* row = xTb + (size_t)(c0 + cc) * N;
            float4 cv = *(const float4*)(row + 4 * tid);
#pragma unroll
            for (int r = 0; r < TM; ++r) {
                float q = (cc == 0) ? qf[r].x : (cc == 1) ? qf[r].y : (cc == 2) ? qf[r].z : qf[r].w;
                acc[r][0] = fmaf(q, cv.x, acc[r][0]);
                acc[r][1] = fmaf(q, cv.y, acc[r][1]);
                acc[r][2] = fmaf(q, cv.z, acc[r][2]);
                acc[r][3] = fmaf(q, cv.w, acc[r][3]);
            }
        }
    }
    for (; c0 < C; ++c0) {                 // remainder (layer 1: C=3)
        const float* row = xTb + (size_t)c0 * N;
        float4 cv = *(const float4*)(row + 4 * tid);
        float q[TM];
#pragma unroll
        for (int r = 0; r < TM; ++r) q[r] = feat[((size_t)b * N + n0 + r) * fs + c0];
#pragma unroll
        for (int r = 0; r < TM; ++r) {
            acc[r][0] = fmaf(q[r], cv.x, acc[r][0]);
            acc[r][1] = fmaf(q[r], cv.y, acc[r][1]);
            acc[r][2] = fmaf(q[r], cv.z, acc[r][2]);
            acc[r][3] = fmaf(q[r], cv.w, acc[r][3]);
        }
    }
    {
        const float* xxb = xx + (size_t)b * N;
        float4 xv = *(const float4*)(xxb + 4 * tid);
        float xq[TM];
#pragma unroll
        for (int r = 0; r < TM; ++r) xq[r] = xxb[n0 + r];
#pragma unroll
        for (int r = 0; r < TM; ++r) {
            float4 d;
            d.x = 2.f * acc[r][0] - xq[r] - xv.x;
            d.y = 2.f * acc[r][1] - xq[r] - xv.y;
            d.z = 2.f * acc[r][2] - xq[r] - xv.z;
            d.w = 2.f * acc[r][3] - xq[r] - xv.w;
            *(float4*)&dist[r][4 * tid] = d;
        }
    }
    __syncthreads();

    // ---------------- phase B: one row per wave; u32 keys; one packed u64 reduce per round
    // lane element (j,i): m = j*256 + 4*lane + i ; slot = j*4+i (ascending slot == ascending m per lane)
    int lane = tid & 63;
    int r = tid >> 6;
    unsigned int key[8][4];
#pragma unroll
    for (int j = 0; j < 8; ++j) {
        float4 v = *(const float4*)&dist[r][j * 256 + 4 * lane];
        key[j][0] = fkey(v.x);
        key[j][1] = fkey(v.y);
        key[j][2] = fkey(v.z);
        key[j][3] = fkey(v.w);
    }
    int resm = 0;
    for (int k = 0; k < 20; ++k) {
        // per-lane best (key, slot): strict > keeps FIRST (min-m) slot among ties
        unsigned int bk = key[0][0];
        unsigned int bs = 0;
#pragma unroll
        for (int j = 0; j < 8; ++j)
#pragma unroll
            for (int i = 0; i < 4; ++i) {
                if (j == 0 && i == 0) continue;
                unsigned int kk = key[j][i];
                bool g = kk > bk;
                bk = g ? kk : bk;
                bs = g ? (unsigned int)(j * 4 + i) : bs;
            }
        unsigned int m = ((bs & ~3u) << 6) | ((unsigned int)lane << 2) | (bs & 3u);
        unsigned long long P = ((unsigned long long)bk << 16) | (unsigned long long)(0xFFFFu - m);
#pragma unroll
        for (int s = 1; s < 64; s <<= 1) {
            unsigned long long o = __shfl_xor(P, s);
            P = P > o ? P : o;
        }
        unsigned int mm = 0xFFFFu - (unsigned int)(P & 0xFFFFu);
        // purge exactly element mm
        unsigned int glane = (mm >> 2) & 63u;
        unsigned int gslot = ((mm >> 8) << 2) | (mm & 3u);
        unsigned int pa = ((unsigned int)lane == glane) ? gslot : 0xFFFFu;
#pragma unroll
        for (int j = 0; j < 8; ++j)
#pragma unroll
            for (int i = 0; i < 4; ++i)
                key[j][i] = (pa == (unsigned int)(j * 4 + i)) ? 0u : key[j][i];
        if (lane == k) resm = (int)mm;
    }
    if (lane < 20) idxOut[((size_t)b * N + n0 + r) * 20 + lane] = resm;
}

// ------------------------------------------------------------ MFMA edgeconv, hi/lo split (3 MFMA per product)
template <int CI, int CO, int TN, int WAVES, int NKC>
__global__ __launch_bounds__(WAVES * 64) void
edgeconv_mfma(const float* __restrict__ feat, int fs, const int* __restrict__ idx,
              const unsigned short* __restrict__ Wh, const unsigned short* __restrict__ Wl,
              const float* __restrict__ gp, const float* __restrict__ bp,
              const float* __restrict__ mp, const float* __restrict__ vp,
              float* __restrict__ outBase) {
    constexpr int N = 2048, K = 20;
    constexpr int C2 = 2 * CI;
    constexpr int C2P = (C2 < 32) ? 32 : C2;
    constexpr int KS = C2P / 32;
    constexpr int KSC = KS / NKC;
    constexpr int CCOLS = KSC * 32;
    constexpr int CHB = CCOLS * 2;
    constexpr int OT = CO / 16;
    constexpr int OTW = OT / WAVES;
    constexpr int M = TN * K;
    constexpr int MT = M / 16;
    constexpr int CH = CCOLS / 8;
    constexpr int SWZ = (CHB >= 128) ? 7 : (CHB / 16 - 1);
    constexpr int THREADS = WAVES * 64;

    int b  = blockIdx.x & 7;
    int n0 = (blockIdx.x >> 3) * TN;
    int tid = threadIdx.x;
    int lane = tid & 63, wv = tid >> 6;

    __shared__ float ctr[TN][CI];
    __shared__ int nb[M];
    __shared__ __align__(16) unsigned char Eh[M * CHB];
    __shared__ __align__(16) unsigned char El[M * CHB];

    for (int e = tid; e < TN * CI; e += THREADS) {
        int ln = e / CI, c = e % CI;
        ctr[ln][c] = feat[((size_t)b * N + n0 + ln) * fs + c];
    }
    for (int e = tid; e < M; e += THREADS) {
        int k = e / TN, ln = e % TN;
        nb[e] = idx[((size_t)b * N + n0 + ln) * K + k];
    }
    __syncthreads();

    f32x4 acc[MT][OTW];
#pragma unroll
    for (int mt = 0; mt < MT; ++mt)
#pragma unroll
        for (int ot = 0; ot < OTW; ++ot)
#pragma unroll
            for (int rr = 0; rr < 4; ++rr) acc[mt][ot][rr] = 0.f;

    for (int kc = 0; kc < NKC; ++kc) {
        if (kc) __syncthreads();
        for (int e = tid; e < M * CH; e += THREADS) {
            int mrow = e / CH, ch = e - mrow * CH;
            int c0 = kc * CCOLS + ch * 8;
            int ln = mrow % TN;
            float v[8];
            if constexpr (CI >= 8) {
                if (c0 < CI) {
#pragma unroll
                    for (int j = 0; j < 8; ++j) v[j] = ctr[ln][c0 + j];
                } else {
                    int c1 = c0 - CI;
                    const float* nrow = feat + ((size_t)b * N + nb[mrow]) * fs + c1;
                    float4 a  = *(const float4*)nrow;
                    float4 b4 = *(const float4*)(nrow + 4);
                    v[0] = a.x  - ctr[ln][c1 + 0];
                    v[1] = a.y  - ctr[ln][c1 + 1];
                    v[2] = a.z  - ctr[ln][c1 + 2];
                    v[3] = a.w  - ctr[ln][c1 + 3];
                    v[4] = b4.x - ctr[ln][c1 + 4];
                    v[5] = b4.y - ctr[ln][c1 + 5];
                    v[6] = b4.z - ctr[ln][c1 + 6];
                    v[7] = b4.w - ctr[ln][c1 + 7];
                }
            } else {
                if (c0 == 0) {
                    const float* nrow = feat + ((size_t)b * N + nb[mrow]) * fs;
                    v[0] = ctr[ln][0]; v[1] = ctr[ln][1]; v[2] = ctr[ln][2];
                    v[3] = nrow[0] - ctr[ln][0];
                    v[4] = nrow[1] - ctr[ln][1];
                    v[5] = nrow[2] - ctr[ln][2];
                    v[6] = 0.f; v[7] = 0.f;
                } else {
#pragma unroll
                    for (int j = 0; j < 8; ++j) v[j] = 0.f;
                }
            }
            union { unsigned short u[8]; uint4 v4; } th, tl;
#pragma unroll
            for (int j = 0; j < 8; ++j) hilo(v[j], th.u[j], tl.u[j]);
            int off = mrow * CHB + ((ch * 16) ^ ((mrow & SWZ) << 4));
            *(uint4*)&Eh[off] = th.v4;
            *(uint4*)&El[off] = tl.v4;
        }
        __syncthreads();

        bf16x8 Bh[OTW][KSC], Bl[OTW][KSC];
#pragma unroll
        for (int ot = 0; ot < OTW; ++ot)
#pragma unroll
            for (int ksc = 0; ksc < KSC; ++ksc) {
                size_t fi = (size_t)((((wv * OTW + ot) * KS + kc * KSC + ksc) * 64 + lane)) << 3;
                Bh[ot][ksc] = *(const bf16x8*)(Wh + fi);
                Bl[ot][ksc] = *(const bf16x8*)(Wl + fi);
            }

#pragma unroll
        for (int mt = 0; mt < MT; ++mt) {
            int r0 = mt * 16 + (lane & 15);
            int cb = (lane >> 4) << 4;
            bf16x8 Ah[KSC], Al[KSC];
#pragma unroll
            for (int ksc = 0; ksc < KSC; ++ksc) {
                int off = r0 * CHB + (((ksc << 6) + cb) ^ ((r0 & SWZ) << 4));
                Ah[ksc] = *(const bf16x8*)&Eh[off];
                Al[ksc] = *(const bf16x8*)&El[off];
            }
#pragma unroll
            for (int ksc = 0; ksc < KSC; ++ksc)
#pragma unroll
                for (int ot = 0; ot < OTW; ++ot) {
                    acc[mt][ot] = __builtin_amdgcn_mfma_f32_16x16x32_bf16(Al[ksc], Bh[ot][ksc], acc[mt][ot], 0, 0, 0);
                    acc[mt][ot] = __builtin_amdgcn_mfma_f32_16x16x32_bf16(Ah[ksc], Bl[ot][ksc], acc[mt][ot], 0, 0, 0);
                    acc[mt][ot] = __builtin_amdgcn_mfma_f32_16x16x32_bf16(Ah[ksc], Bh[ot][ksc], acc[mt][ot], 0, 0, 0);
                }
        }
    }

#pragma unroll
    for (int ot = 0; ot < OTW; ++ot) {
        f32x4 v;
#pragma unroll
        for (int rr = 0; rr < 4; ++rr) {
            float m = acc[0][ot][rr];
#pragma unroll
            for (int mt = 1; mt < MT; ++mt) m = fmaxf(m, acc[mt][ot][rr]);
            if constexpr (TN == 4) m = fmaxf(m, __shfl_xor(m, 16));
            m = fmaxf(m, __shfl_xor(m, 32));
            v[rr] = m;
        }
        int o = (wv * OTW + ot) * 16 + (lane & 15);
        float s  = gp[o] * rsqrtf(vp[o] + EPS);
        float sh = bp[o] - mp[o] * s;
        bool valid = (TN == 8) ? (lane < 32) : (lane < 16);
        if (valid) {
            int lnb = (TN == 8) ? ((lane >> 4) << 2) : 0;
#pragma unroll
            for (int rr = 0; rr < 4; ++rr) {
                float h = fmaf(v[rr], s, sh);
                h = h > 0.f ? h : 0.2f * h;
                outBase[((size_t)b * N + n0 + lnb + rr) * 512 + o] = h;
            }
        }
    }
}

// ------------------------------------------------------------ global 512x512 MFMA (hi/lo), streaming K-loop
__global__ __launch_bounds__(256) void
global_mfma(const float* __restrict__ xcat,
            const unsigned short* __restrict__ Wh, const unsigned short* __restrict__ Wl,
            const float* __restrict__ gg, const float* __restrict__ bg,
            const float* __restrict__ mg, const float* __restrict__ vg,
            unsigned int* __restrict__ keys) {
    const int N = 2048, CV = 512;
    int b     = blockIdx.x & 7;
    int t     = blockIdx.x >> 3;
    int n0    = (t & 63) * 32;
    int colh  = t >> 6;
    int tid = threadIdx.x, lane = tid & 63, wv = tid >> 6;
    int obase = colh * 16 + wv * 4;

    f32x4 acc0[4], acc1[4];
#pragma unroll
    for (int ot = 0; ot < 4; ++ot)
#pragma unroll
        for (int rr = 0; rr < 4; ++rr) { acc0[ot][rr] = 0.f; acc1[ot][rr] = 0.f; }

    const float* arow0 = xcat + ((size_t)b * N + n0 +      (lane & 15)) * CV + ((lane >> 4) << 3);
    const float* arow1 = xcat + ((size_t)b * N + n0 + 16 + (lane & 15)) * CV + ((lane >> 4) << 3);

    for (int ks = 0; ks < 16; ++ks) {
        bf16x8 Ah0, Al0, Ah1, Al1;
        {
            float4 a  = *(const float4*)(arow0 + ks * 32);
            float4 b4 = *(const float4*)(arow0 + ks * 32 + 4);
            union { unsigned short u[8]; bf16x8 v; } ch, cl;
            hilo(a.x,  ch.u[0], cl.u[0]); hilo(a.y,  ch.u[1], cl.u[1]);
            hilo(a.z,  ch.u[2], cl.u[2]); hilo(a.w,  ch.u[3], cl.u[3]);
            hilo(b4.x, ch.u[4], cl.u[4]); hilo(b4.y, ch.u[5], cl.u[5]);
            hilo(b4.z, ch.u[6], cl.u[6]); hilo(b4.w, ch.u[7], cl.u[7]);
            Ah0 = ch.v; Al0 = cl.v;
        }
        {
            float4 a  = *(const float4*)(arow1 + ks * 32);
            float4 b4 = *(const float4*)(arow1 + ks * 32 + 4);
            union { unsigned short u[8]; bf16x8 v; } ch, cl;
            hilo(a.x,  ch.u[0], cl.u[0]); hilo(a.y,  ch.u[1], cl.u[1]);
            hilo(a.z,  ch.u[2], cl.u[2]); hilo(a.w,  ch.u[3], cl.u[3]);
            hilo(b4.x, ch.u[4], cl.u[4]); hilo(b4.y, ch.u[5], cl.u[5]);
            hilo(b4.z, ch.u[6], cl.u[6]); hilo(b4.w, ch.u[7], cl.u[7]);
            Ah1 = ch.v; Al1 = cl.v;
        }
#pragma unroll
        for (int ot = 0; ot < 4; ++ot) {
            size_t fi = (size_t)((((obase + ot) * 16 + ks) * 64 + lane)) << 3;
            bf16x8 Bh = *(const bf16x8*)(Wh + fi);
            bf16x8 Bl = *(const bf16x8*)(Wl + fi);
            acc0[ot] = __builtin_amdgcn_mfma_f32_16x16x32_bf16(Al0, Bh, acc0[ot], 0, 0, 0);
            acc0[ot] = __builtin_amdgcn_mfma_f32_16x16x32_bf16(Ah0, Bl, acc0[ot], 0, 0, 0);
            acc0[ot] = __builtin_amdgcn_mfma_f32_16x16x32_bf16(Ah0, Bh, acc0[ot], 0, 0, 0);
            acc1[ot] = __builtin_amdgcn_mfma_f32_16x16x32_bf16(Al1, Bh, acc1[ot], 0, 0, 0);
            acc1[ot] = __builtin_amdgcn_mfma_f32_16x16x32_bf16(Ah1, Bl, acc1[ot], 0, 0, 0);
            acc1[ot] = __builtin_amdgcn_mfma_f32_16x16x32_bf16(Ah1, Bh, acc1[ot], 0, 0, 0);
        }
    }

#pragma unroll
    for (int ot = 0; ot < 4; ++ot) {
        f32x4 v;
#pragma unroll
        for (int rr = 0; rr < 4; ++rr) {
            float m = fmaxf(acc0[ot][rr], acc1[ot][rr]);
            m = fmaxf(m, __shfl_xor(m, 16));
            m = fmaxf(m, __shfl_xor(m, 32));
            v[rr] = m;
        }
        int o = (obase + ot) * 16 + (lane & 15);
        float s  = gg[o] * rsqrtf(vg[o] + EPS);
        float sh = bg[o] - mg[o] * s;
        if (lane < 16) {
            float hm = -INFINITY;
#pragma unroll
            for (int rr = 0; rr < 4; ++rr) {
                float h = fmaf(v[rr], s, sh);
                h = h > 0.f ? h : 0.2f * h;
                hm = fmaxf(hm, h);
            }
            atomicMax(&keys[b * 512 + o], fkey(hm));
        }
    }
}

__global__ void decode_kernel(const unsigned int* __restrict__ keys, float* __restrict__ out) {
    int id = blockIdx.x * 256 + threadIdx.x;
    if (id < 8 * 512) out[id] = funkey(keys[id]);
}

// ---------------------------------------------------------------- launcher
extern "C" void kernel_launch(void* const* d_in, const int* in_sizes, int n_in,
                              void* d_out, int out_size, void* d_ws, size_t ws_size,
                              hipStream_t stream) {
    const int B = 8, N = 2048, K = 20;
    const float* pts = (const float*)d_in[0];
    const float* w1 = (const float*)d_in[1];
    const float *g1 = (const float*)d_in[2], *b1 = (const float*)d_in[3],
                *m1 = (const float*)d_in[4], *v1 = (const float*)d_in[5];
    const float* w2 = (const float*)d_in[6];
    const float *g2 = (const float*)d_in[7], *b2 = (const float*)d_in[8],
                *m2 = (const float*)d_in[9], *v2 = (const float*)d_in[10];
    const float* w3 = (const float*)d_in[11];
    const float *g3 = (const float*)d_in[12], *b3 = (const float*)d_in[13],
                *m3 = (const float*)d_in[14], *v3 = (const float*)d_in[15];
    const float* w4 = (const float*)d_in[16];
    const float *g4 = (const float*)d_in[17], *b4 = (const float*)d_in[18],
                *m4 = (const float*)d_in[19], *v4 = (const float*)d_in[20];
    const float* wg = (const float*)d_in[21];
    const float *gg = (const float*)d_in[22], *bg = (const float*)d_in[23],
                *mg = (const float*)d_in[24], *vg = (const float*)d_in[25];

    // workspace layout
    float* ws   = (float*)d_ws;
    float* xcat = ws;                                    // 8*2048*512
    float* xT   = xcat + (size_t)B * N * 512;            // 8*128*2048
    float* xx   = xT + (size_t)B * 128 * N;              // 8*2048
    int*   idx  = (int*)(xx + B * N);                    // 8*2048*20
    unsigned short* wf1h = (unsigned short*)(idx + (size_t)B * N * K);
    unsigned short* wf1l = wf1h + 64 * 32;
    unsigned short* wf2h = wf1l + 64 * 32;
    unsigned short* wf2l = wf2h + 64 * 128;
    unsigned short* wf3h = wf2l + 64 * 128;
    unsigned short* wf3l = wf3h + 128 * 128;
    unsigned short* wf4h = wf3l + 128 * 128;
    unsigned short* wf4l = wf4h + 256 * 256;
    unsigned short* wfgh = wf4l + 256 * 256;
    unsigned short* wfgl = wfgh + 512 * 512;
    unsigned int* keys  = (unsigned int*)(wfgl + 512 * 512);

    // pack weight fragments (bf16 hi/lo)
    wfrag_kernel<<<(64 * 32 + 255) / 256, 256, 0, stream>>>(w1, 64, 6, 32, wf1h, wf1l);
    wfrag_kernel<<<(64 * 128 + 255) / 256, 256, 0, stream>>>(w2, 64, 128, 128, wf2h, wf2l);
    wfrag_kernel<<<(128 * 128 + 255) / 256, 256, 0, stream>>>(w3, 128, 128, 128, wf3h, wf3l);
    wfrag_kernel<<<(256 * 256 + 255) / 256, 256, 0, stream>>>(w4, 256, 256, 256, wf4h, wf4l);
    wfrag_kernel<<<(512 * 512 + 255) / 256, 256, 0, stream>>>(wg, 512, 512, 512, wfgh, wfgl);

    // ---- layer 1: C=3 -> 64, out offset 0
    transpose_feat_kernel<<<(B * 3 * N + 255) / 256, 256, 0, stream>>>(pts, 3, 3, xT);
    sumsq_kernel<<<(B * N + 255) / 256, 256, 0, stream>>>(xT, 3, xx);
    dist_topk_kernel<<<B * (N / 8), 512, 0, stream>>>(xT, pts, 3, xx, 3, idx);
    edgeconv_mfma<3, 64, 8, 4, 1><<<B * (N / 8), 256, 0, stream>>>(pts, 3, idx, wf1h, wf1l, g1, b1, m1, v1, xcat + 0);

    // ---- layer 2: 64 -> 64, out offset 64
    transpose_feat_kernel<<<(B * 64 * N + 255) / 256, 256, 0, stream>>>(xcat + 0, 512, 64, xT);
    sumsq_kernel<<<(B * N + 255) / 256, 256, 0, stream>>>(xT, 64, xx);
    dist_topk_kernel<<<B * (N / 8), 512, 0, stream>>>(xT, xcat + 0, 512, xx, 64, idx);
    edgeconv_mfma<64, 64, 4, 4, 1><<<B * (N / 4), 256, 0, stream>>>(xcat + 0, 512, idx, wf2h, wf2l, g2, b2, m2, v2, xcat + 64);

    // ---- layer 3: 64 -> 128, out offset 128
    transpose_feat_kernel<<<(B * 64 * N + 255) / 256, 256, 0, stream>>>(xcat + 64, 512, 64, xT);
    sumsq_kernel<<<(B * N + 255) / 256, 256, 0, stream>>>(xT, 64, xx);
    dist_topk_kernel<<<B * (N / 8), 512, 0, stream>>>(xT, xcat + 64, 512, xx, 64, idx);
    edgeconv_mfma<64, 128, 4, 8, 1><<<B * (N / 4), 512, 0, stream>>>(xcat + 64, 512, idx, wf3h, wf3l, g3, b3, m3, v3, xcat + 128);

    // ---- layer 4: 128 -> 256, out offset 256 (K-chunked: NKC=2)
    transpose_feat_kernel<<<(B * 128 * N + 255) / 256, 256, 0, stream>>>(xcat + 128, 512, 128, xT);
    sumsq_kernel<<<(B * N + 255) / 256, 256, 0, stream>>>(xT, 128, xx);
    dist_topk_kernel<<<B * (N / 8), 512, 0, stream>>>(xT, xcat + 128, 512, xx, 128, idx);
    edgeconv_mfma<128, 256, 4, 8, 2><<<B * (N / 4), 512, 0, stream>>>(xcat + 128, 512, idx, wf4h, wf4l, g4, b4, m4, v4, xcat + 256);

    // ---- global layer + max over N
    hipMemsetAsync(keys, 0, (size_t)B * 512 * sizeof(unsigned int), stream);
    global_mfma<<<B * 128, 256, 0, stream>>>(xcat, wfgh, wfgl, gg, bg, mg, vg, keys);
    decode_kernel<<<(B * 512 + 255) / 256, 256, 0, stream>>>(keys, (float*)d_out);
}